// Round 7
// baseline (403.293 us; speedup 1.0000x reference)
//
#include <hip/hip_runtime.h>

// Problem constants
#define BB 64
#define II 1152
#define OO 32
#define DD 8
#define HH 16
#define BOH (BB * OO * HH)    // 32768
#define WTILE (OO * DD * HH)  // 4096 floats per i

// Shared per-block shape (R5-proven): NBB=16 b/block, NJB=4 b/thread.
#define NBB  16
#define NBG  4
#define NJB  4

// Fallback (R5-exact) decomposition: 512 blocks.
#define IC_F   9
#define NIC_F  128

// Cooperative decomposition: 256 blocks = 1 block/CU guaranteed schedulable
// (R6's 512 needed exactly 2/CU and was rejected by the runtime's occupancy
// check -> silent zero output; absmax 0.797 == max|ref| was the tell).
#define IC_C   18
#define NIC_C  64
#define NBLK_C (NIC_C * NBG)   // 256
#define NGRP_C (NBLK_C / 64)   // 4

// ---------------------------------------------------------------------------
// DPP add helper (ctrl must be an ICE -> template param).
// ---------------------------------------------------------------------------
template<int CTRL>
__device__ __forceinline__ float dpp_add(float x)
{
    return x + __int_as_float(__builtin_amdgcn_update_dpp(
            0, __float_as_int(x), CTRL, 0xF, 0xF, false));
}

// Sum over each 16-lane row, result in every lane of the row (VALU only).
__device__ __forceinline__ float row_sum16(float x)
{
    x = dpp_add<0x121>(x);   // row_ror:1
    x = dpp_add<0x122>(x);   // row_ror:2
    x = dpp_add<0x124>(x);   // row_ror:4
    x = dpp_add<0x128>(x);   // row_ror:8
    return x;
}

// lane l gets x[l] + x[l^32] — VALU permlane32_swap.
__device__ __forceinline__ float add_xor32(float x)
{
#if __has_builtin(__builtin_amdgcn_permlane32_swap)
    auto r = __builtin_amdgcn_permlane32_swap(
        __float_as_uint(x), __float_as_uint(x), false, false);
    return __uint_as_float(r[0]) + __uint_as_float(r[1]);
#else
    return x + __shfl_xor(x, 32, 64);
#endif
}

// lane l gets x[l] + x[l^16] — VALU permlane16_swap.
__device__ __forceinline__ float add_xor16(float x)
{
#if __has_builtin(__builtin_amdgcn_permlane16_swap)
    auto r = __builtin_amdgcn_permlane16_swap(
        __float_as_uint(x), __float_as_uint(x), false, false);
    return __uint_as_float(r[0]) + __uint_as_float(r[1]);
#else
    return x + __int_as_float(__builtin_amdgcn_ds_swizzle(__float_as_int(x), 0x401F));
#endif
}

// ---------------------------------------------------------------------------
// 5-bit XOR swizzle on a float index within one 4096-float W tile (involution,
// 16-B groups stay contiguous; read-side bank histogram uniform 8/bank).
// ---------------------------------------------------------------------------
__device__ __forceinline__ int wswz(int f) { return f ^ (((f >> 7) & 31) << 2); }

// Stage one 16 KB W tile global->LDS via DMA (linear dest, pre-swizzled src).
__device__ __forceinline__ void stage_w_tile(const float* __restrict__ wg,
                                             float* __restrict__ wn, int tid)
{
    #pragma unroll
    for (int j = 0; j < 4; j++) {
        const int P = (tid + j * 256) * 4;
        const int g = wswz(P);
        __builtin_amdgcn_global_load_lds(
            (const __attribute__((address_space(1))) void*)(wg + g),
            (__attribute__((address_space(3))) void*)(wn + P),
            16, 0, 0);
    }
}

// ---------------------------------------------------------------------------
// Two-level grid barrier for NBLK_C co-resident blocks (cooperative launch).
// bar: [0..3] group counters (64 blocks each), [8] master, [9] generation.
// Monotonic per-phase targets -> no reset race. System-scope fences give
// release (L2 writeback) on arrival / acquire (cache inv) on exit so plain
// vectorized loads of part/v after the barrier are fresh across XCDs.
// ---------------------------------------------------------------------------
__device__ __forceinline__ void gbar(unsigned* __restrict__ bar, int phase, int bi)
{
    __syncthreads();
    if (threadIdx.x == 0) {
        __threadfence_system();   // release my block's writes
        unsigned* grp    = bar + (bi >> 6);
        unsigned* master = bar + 8;
        unsigned* gen    = bar + 9;
        const unsigned a = __hip_atomic_fetch_add(grp, 1u, __ATOMIC_ACQ_REL,
                                                  __HIP_MEMORY_SCOPE_AGENT) + 1;
        if (a == (unsigned)((phase + 1) * 64)) {
            const unsigned m = __hip_atomic_fetch_add(master, 1u, __ATOMIC_ACQ_REL,
                                                      __HIP_MEMORY_SCOPE_AGENT) + 1;
            if (m == (unsigned)((phase + 1) * NGRP_C)) {
                __hip_atomic_store(gen, (unsigned)(phase + 1), __ATOMIC_RELEASE,
                                   __HIP_MEMORY_SCOPE_AGENT);
            }
        }
        while (__hip_atomic_load(gen, __ATOMIC_ACQUIRE,
                                 __HIP_MEMORY_SCOPE_AGENT) < (unsigned)(phase + 1)) {
            __builtin_amdgcn_s_sleep(2);
        }
        __threadfence_system();   // acquire: invalidate before plain reads
    }
    __syncthreads();
}

// ---------------------------------------------------------------------------
// Persistent cooperative kernel: 3 routing iterations + reduces, ONE dispatch.
// Tests the dispatch-overhead theory (5 structurally different 6-dispatch
// variants all pinned at ~40 us/pass vs 5-8 us intra-kernel models).
// Grid (NIC_C, NBG) = 256 blocks x 256 thr; per iteration p:
//   R5 pass body (DMA W dbuf, broadcast u, VALU softmax) over IC_C=18 i's
//   -> 8.4 MB part slab; gbar; reduce (256 blocks x 32 t4, LDS tree, DPP
//   squash) -> v_p / out; gbar (except last). W is XCD-L2-hot for p>=1.
// ---------------------------------------------------------------------------
__global__ __launch_bounds__(256)
void routing_kernel(const float* __restrict__ u, const float* __restrict__ w,
                    float* __restrict__ part, float* __restrict__ v0,
                    float* __restrict__ v1, float* __restrict__ out,
                    unsigned* __restrict__ bar)
{
    __shared__ __align__(16) float Wsh[2][WTILE];   // 32 KB
    __shared__ float4 red[8][32];                   // 4 KB

    const int tid   = threadIdx.x;
    const int o     = tid & 31;
    const int hh    = (tid >> 5) & 1;
    const int bq    = tid >> 6;
    const int bx    = blockIdx.x;          // i-chunk (0..63)
    const int by    = blockIdx.y;          // b-group (0..3)
    const int bi    = by * NIC_C + bx;     // 0..255
    const int bbase = by * NBB;
    const int i0    = bx * IC_C;
    const int hofs  = hh * 8;
    const int swm   = o << 2;
    const int orow  = o * (DD * HH);

    int phase = 0;

    for (int p = 0; p < 3; ++p) {
        // ---- vsum (fresh: acquire-fenced barrier precedes for p>=1) ----
        float vsum[NJB][8];
        if (p >= 1) {
            #pragma unroll
            for (int jb = 0; jb < NJB; jb++) {
                const int b = bbase + bq * NJB + jb;
                const float* pp = v0 + ((b * OO + o) * HH + hofs);
                float4 a = *(const float4*)pp;
                float4 c = *(const float4*)(pp + 4);
                vsum[jb][0] = a.x; vsum[jb][1] = a.y; vsum[jb][2] = a.z; vsum[jb][3] = a.w;
                vsum[jb][4] = c.x; vsum[jb][5] = c.y; vsum[jb][6] = c.z; vsum[jb][7] = c.w;
                if (p == 2) {
                    const float* q = v1 + ((b * OO + o) * HH + hofs);
                    float4 a2 = *(const float4*)q;
                    float4 c2 = *(const float4*)(q + 4);
                    vsum[jb][0] += a2.x; vsum[jb][1] += a2.y; vsum[jb][2] += a2.z; vsum[jb][3] += a2.w;
                    vsum[jb][4] += c2.x; vsum[jb][5] += c2.y; vsum[jb][6] += c2.z; vsum[jb][7] += c2.w;
                }
            }
        }

        // ---- pass body (R5 structure, IC_C iterations) ----
        stage_w_tile(w + (size_t)i0 * WTILE, Wsh[0], tid);

        float sacc[NJB][8];
        #pragma unroll
        for (int jb = 0; jb < NJB; jb++)
            #pragma unroll
            for (int h2 = 0; h2 < 8; h2++) sacc[jb][h2] = 0.f;

        __syncthreads();   // drains vmcnt(0): Wsh[0] DMA complete

        for (int ii = 0; ii < IC_C; ii++) {
            const float* wcur = Wsh[ii & 1];
            if (ii + 1 < IC_C)
                stage_w_tile(w + (size_t)(i0 + ii + 1) * WTILE, Wsh[(ii + 1) & 1], tid);

            float us[NJB][8];
            #pragma unroll
            for (int jb = 0; jb < NJB; jb++) {
                const float* ub = u + ((size_t)(bbase + bq * NJB + jb) * II + (i0 + ii)) * DD;
                float4 a = *(const float4*)ub;
                float4 c = *(const float4*)(ub + 4);
                us[jb][0] = a.x; us[jb][1] = a.y; us[jb][2] = a.z; us[jb][3] = a.w;
                us[jb][4] = c.x; us[jb][5] = c.y; us[jb][6] = c.z; us[jb][7] = c.w;
            }

            float uh[NJB][8];
            #pragma unroll
            for (int jb = 0; jb < NJB; jb++)
                #pragma unroll
                for (int h2 = 0; h2 < 8; h2++) uh[jb][h2] = 0.f;
            #pragma unroll
            for (int d = 0; d < DD; d++) {
                const int ba  = (d * HH + hofs    ) ^ swm;
                const int bb2 = (d * HH + hofs + 4) ^ swm;
                float4 wa = *(const float4*)&wcur[orow + ba];
                float4 wb = *(const float4*)&wcur[orow + bb2];
                const float wv[8] = {wa.x, wa.y, wa.z, wa.w, wb.x, wb.y, wb.z, wb.w};
                #pragma unroll
                for (int jb = 0; jb < NJB; jb++)
                    #pragma unroll
                    for (int h2 = 0; h2 < 8; h2++)
                        uh[jb][h2] = fmaf(us[jb][d], wv[h2], uh[jb][h2]);
            }

            float cc[NJB];
            if (p == 0) {
                #pragma unroll
                for (int jb = 0; jb < NJB; jb++) cc[jb] = 1.0f / 32.0f;
            } else {
                #pragma unroll
                for (int jb = 0; jb < NJB; jb++) {
                    float lg = 0.f;
                    #pragma unroll
                    for (int h2 = 0; h2 < 8; h2++)
                        lg = fmaf(vsum[jb][h2], uh[jb][h2], lg);
                    lg = add_xor32(lg);
                    const float e = __expf(lg);
                    const float se = add_xor16(row_sum16(e));
                    cc[jb] = __fdividef(e, se);
                }
            }

            #pragma unroll
            for (int jb = 0; jb < NJB; jb++)
                #pragma unroll
                for (int h2 = 0; h2 < 8; h2++)
                    sacc[jb][h2] = fmaf(cc[jb], uh[jb][h2], sacc[jb][h2]);

            __syncthreads();
        }

        // ---- emit partial slab ----
        #pragma unroll
        for (int jb = 0; jb < NJB; jb++) {
            const int b = bbase + bq * NJB + jb;
            float* pp = part + ((size_t)bx * BB + b) * (OO * HH) + o * HH + hofs;
            *(float4*)pp       = make_float4(sacc[jb][0], sacc[jb][1], sacc[jb][2], sacc[jb][3]);
            *(float4*)(pp + 4) = make_float4(sacc[jb][4], sacc[jb][5], sacc[jb][6], sacc[jb][7]);
        }

        gbar(bar, phase++, bi);   // partials visible device-wide

        // ---- reduce + squash: 256 blocks x 32 t4-slices, 64 chunks ----
        {
            float* vt = (p == 0) ? v0 : (p == 1) ? v1 : out;
            const int t4l = tid & 31;          // t4 within block
            const int icp = tid >> 5;          // 8 chunk groups (8 chunks each)
            const int t4  = bi * 32 + t4l;     // 0..8191

            const float4* pr = (const float4*)part + t4;
            float4 acc = make_float4(0.f, 0.f, 0.f, 0.f);
            #pragma unroll
            for (int k = 0; k < 8; k++) {
                float4 x = pr[(size_t)(icp * 8 + k) * (BOH / 4)];
                acc.x += x.x; acc.y += x.y; acc.z += x.z; acc.w += x.w;
            }
            red[icp][t4l] = acc;
            __syncthreads();

            if (tid < 32) {
                float4 a = red[0][t4l];
                #pragma unroll
                for (int j = 1; j < 8; j++) {
                    float4 x = red[j][t4l];
                    a.x += x.x; a.y += x.y; a.z += x.z; a.w += x.w;
                }
                float sq = a.x * a.x + a.y * a.y + a.z * a.z + a.w * a.w;
                sq = dpp_add<0xB1>(sq);   // quad_perm [1,0,3,2]
                sq = dpp_add<0x4E>(sq);   // quad_perm [2,3,0,1]
                const float scale = (sq / (1.f + sq)) * rsqrtf(sq + 1e-8f);
                a.x *= scale; a.y *= scale; a.z *= scale; a.w *= scale;
                ((float4*)vt)[t4] = a;
            }
        }

        if (p < 2) gbar(bar, phase++, bi);   // v_p visible device-wide
    }
}

// ---------------------------------------------------------------------------
// Fallback: R5-exact 6-dispatch path (proven 137 us).
// ---------------------------------------------------------------------------
template<int PASS, bool ATOMIC>
__global__ __launch_bounds__(256)
void pass_kernel(const float* __restrict__ u, const float* __restrict__ w,
                 const float* __restrict__ pv0, const float* __restrict__ pv1,
                 float* __restrict__ out)
{
    __shared__ __align__(16) float Wsh[2][WTILE];

    const int tid   = threadIdx.x;
    const int o     = tid & 31;
    const int hh    = (tid >> 5) & 1;
    const int bq    = tid >> 6;
    const int bbase = blockIdx.y * NBB;
    const int i0    = blockIdx.x * IC_F;
    const int hofs  = hh * 8;
    const int swm   = o << 2;
    const int orow  = o * (DD * HH);

    stage_w_tile(w + (size_t)i0 * WTILE, Wsh[0], tid);

    float vsum[NJB][8];
    if (PASS >= 1) {
        #pragma unroll
        for (int jb = 0; jb < NJB; jb++) {
            const int b = bbase + bq * NJB + jb;
            const float* p = pv0 + ((b * OO + o) * HH + hofs);
            float4 a = *(const float4*)p;
            float4 c = *(const float4*)(p + 4);
            vsum[jb][0] = a.x; vsum[jb][1] = a.y; vsum[jb][2] = a.z; vsum[jb][3] = a.w;
            vsum[jb][4] = c.x; vsum[jb][5] = c.y; vsum[jb][6] = c.z; vsum[jb][7] = c.w;
            if (PASS == 2) {
                const float* q = pv1 + ((b * OO + o) * HH + hofs);
                float4 a2 = *(const float4*)q;
                float4 c2 = *(const float4*)(q + 4);
                vsum[jb][0] += a2.x; vsum[jb][1] += a2.y; vsum[jb][2] += a2.z; vsum[jb][3] += a2.w;
                vsum[jb][4] += c2.x; vsum[jb][5] += c2.y; vsum[jb][6] += c2.z; vsum[jb][7] += c2.w;
            }
        }
    }

    float sacc[NJB][8];
    #pragma unroll
    for (int jb = 0; jb < NJB; jb++)
        #pragma unroll
        for (int h2 = 0; h2 < 8; h2++) sacc[jb][h2] = 0.f;

    __syncthreads();

    for (int ii = 0; ii < IC_F; ii++) {
        const float* wcur = Wsh[ii & 1];
        if (ii + 1 < IC_F)
            stage_w_tile(w + (size_t)(i0 + ii + 1) * WTILE, Wsh[(ii + 1) & 1], tid);

        float us[NJB][8];
        #pragma unroll
        for (int jb = 0; jb < NJB; jb++) {
            const float* ub = u + ((size_t)(bbase + bq * NJB + jb) * II + (i0 + ii)) * DD;
            float4 a = *(const float4*)ub;
            float4 c = *(const float4*)(ub + 4);
            us[jb][0] = a.x; us[jb][1] = a.y; us[jb][2] = a.z; us[jb][3] = a.w;
            us[jb][4] = c.x; us[jb][5] = c.y; us[jb][6] = c.z; us[jb][7] = c.w;
        }

        float uh[NJB][8];
        #pragma unroll
        for (int jb = 0; jb < NJB; jb++)
            #pragma unroll
            for (int h2 = 0; h2 < 8; h2++) uh[jb][h2] = 0.f;
        #pragma unroll
        for (int d = 0; d < DD; d++) {
            const int ba  = (d * HH + hofs    ) ^ swm;
            const int bb2 = (d * HH + hofs + 4) ^ swm;
            float4 wa = *(const float4*)&wcur[orow + ba];
            float4 wb = *(const float4*)&wcur[orow + bb2];
            const float wv[8] = {wa.x, wa.y, wa.z, wa.w, wb.x, wb.y, wb.z, wb.w};
            #pragma unroll
            for (int jb = 0; jb < NJB; jb++)
                #pragma unroll
                for (int h2 = 0; h2 < 8; h2++)
                    uh[jb][h2] = fmaf(us[jb][d], wv[h2], uh[jb][h2]);
        }

        float cc[NJB];
        if (PASS == 0) {
            #pragma unroll
            for (int jb = 0; jb < NJB; jb++) cc[jb] = 1.0f / 32.0f;
        } else {
            #pragma unroll
            for (int jb = 0; jb < NJB; jb++) {
                float lg = 0.f;
                #pragma unroll
                for (int h2 = 0; h2 < 8; h2++)
                    lg = fmaf(vsum[jb][h2], uh[jb][h2], lg);
                lg = add_xor32(lg);
                const float e = __expf(lg);
                const float se = add_xor16(row_sum16(e));
                cc[jb] = __fdividef(e, se);
            }
        }

        #pragma unroll
        for (int jb = 0; jb < NJB; jb++)
            #pragma unroll
            for (int h2 = 0; h2 < 8; h2++)
                sacc[jb][h2] = fmaf(cc[jb], uh[jb][h2], sacc[jb][h2]);

        __syncthreads();
    }

    #pragma unroll
    for (int jb = 0; jb < NJB; jb++) {
        const int b = bbase + bq * NJB + jb;
        if (ATOMIC) {
            float* p = out + ((b * OO + o) * HH + hofs);
            #pragma unroll
            for (int h2 = 0; h2 < 8; h2++) atomicAdd(p + h2, sacc[jb][h2]);
        } else {
            float* p = out + ((size_t)blockIdx.x * BB + b) * (OO * HH) + o * HH + hofs;
            *(float4*)p       = make_float4(sacc[jb][0], sacc[jb][1], sacc[jb][2], sacc[jb][3]);
            *(float4*)(p + 4) = make_float4(sacc[jb][4], sacc[jb][5], sacc[jb][6], sacc[jb][7]);
        }
    }
}

// R4-proven wide reduce (256 blocks, 128 chunks) for the fallback path.
__global__ __launch_bounds__(256)
void reduce_squash_wide_kernel(const float* __restrict__ part, float* __restrict__ v)
{
    const int t4l = threadIdx.x & 31;
    const int icp = threadIdx.x >> 5;
    const int t4  = blockIdx.x * 32 + t4l;

    const float4* p = (const float4*)part + t4;
    float4 acc = make_float4(0.f, 0.f, 0.f, 0.f);
    #pragma unroll
    for (int k = 0; k < NIC_F / 8; k++) {
        float4 x = p[(size_t)(icp * (NIC_F / 8) + k) * (BOH / 4)];
        acc.x += x.x; acc.y += x.y; acc.z += x.z; acc.w += x.w;
    }

    __shared__ float4 red[8][32];
    red[icp][t4l] = acc;
    __syncthreads();

    if (threadIdx.x < 32) {
        float4 a = red[0][t4l];
        #pragma unroll
        for (int j = 1; j < 8; j++) {
            float4 x = red[j][t4l];
            a.x += x.x; a.y += x.y; a.z += x.z; a.w += x.w;
        }
        float sq = a.x * a.x + a.y * a.y + a.z * a.z + a.w * a.w;
        sq = dpp_add<0xB1>(sq);
        sq = dpp_add<0x4E>(sq);
        const float scale = (sq / (1.f + sq)) * rsqrtf(sq + 1e-8f);
        a.x *= scale; a.y *= scale; a.z *= scale; a.w *= scale;
        ((float4*)v)[t4] = a;
    }
}

// Standalone squash for the atomic tiny-ws fallback.
__global__ __launch_bounds__(256)
void squash_kernel(const float* __restrict__ s, float* __restrict__ v)
{
    const int t = blockIdx.x * blockDim.x + threadIdx.x;
    if (t >= BB * OO) return;
    const float4* sp = (const float4*)(s + t * HH);
    float4 a = sp[0], b = sp[1], c = sp[2], d = sp[3];
    float sq = a.x*a.x + a.y*a.y + a.z*a.z + a.w*a.w
             + b.x*b.x + b.y*b.y + b.z*b.z + b.w*b.w
             + c.x*c.x + c.y*c.y + c.z*c.z + c.w*c.w
             + d.x*d.x + d.y*d.y + d.z*d.z + d.w*d.w;
    const float scale = (sq / (1.f + sq)) * rsqrtf(sq + 1e-8f);
    a.x *= scale; a.y *= scale; a.z *= scale; a.w *= scale;
    b.x *= scale; b.y *= scale; b.z *= scale; b.w *= scale;
    c.x *= scale; c.y *= scale; c.z *= scale; c.w *= scale;
    d.x *= scale; d.y *= scale; d.z *= scale; d.w *= scale;
    float4* vp = (float4*)(v + t * HH);
    vp[0] = a; vp[1] = b; vp[2] = c; vp[3] = d;
}

extern "C" void kernel_launch(void* const* d_in, const int* in_sizes, int n_in,
                              void* d_out, int out_size, void* d_ws, size_t ws_size,
                              hipStream_t stream)
{
    (void)in_sizes; (void)n_in; (void)out_size;
    const float* u = (const float*)d_in[0];
    const float* w = (const float*)d_in[1];
    float* out = (float*)d_out;

    // Layout sized for the larger (fallback) partial buffer; coop reuses it.
    const size_t partN = (size_t)NIC_F * BOH;
    const size_t need  = (partN + 2 * BOH + 64) * sizeof(float);   // ~17 MB

    if (ws_size >= need) {
        float* part   = (float*)d_ws;
        float* v0     = part + partN;
        float* v1     = v0 + BOH;
        unsigned* bar = (unsigned*)(v1 + BOH);

        bool done = false;
        int dev = 0, coop = 0;
        if (hipGetDevice(&dev) == hipSuccess)
            (void)hipDeviceGetAttribute(&coop, hipDeviceAttributeCooperativeLaunch, dev);
        if (coop) {
            hipMemsetAsync(bar, 0, 16 * sizeof(unsigned), stream);
            void* args[] = {
                (void*)&u, (void*)&w, (void*)&part, (void*)&v0,
                (void*)&v1, (void*)&out, (void*)&bar
            };
            hipError_t e = hipLaunchCooperativeKernel(
                reinterpret_cast<void*>(routing_kernel),
                dim3(NIC_C, NBG), dim3(256), args, 0, stream);
            if (e == hipSuccess) done = true;
            else (void)hipGetLastError();   // clear sticky error, fall back
        }

        if (!done) {
            // R5-exact 6-dispatch path.
            const dim3 grid(NIC_F, NBG), blk(256);
            const int rblocks = BOH / 4 / 32;   // 256

            pass_kernel<0, false><<<grid, blk, 0, stream>>>(u, w, nullptr, nullptr, part);
            reduce_squash_wide_kernel<<<rblocks, 256, 0, stream>>>(part, v0);
            pass_kernel<1, false><<<grid, blk, 0, stream>>>(u, w, v0, nullptr, part);
            reduce_squash_wide_kernel<<<rblocks, 256, 0, stream>>>(part, v1);
            pass_kernel<2, false><<<grid, blk, 0, stream>>>(u, w, v0, v1, part);
            reduce_squash_wide_kernel<<<rblocks, 256, 0, stream>>>(part, out);
        }
    } else {
        // Tiny-ws fallback: atomic path, 6 dispatches.
        float* s0 = (float*)d_ws;
        float* s1 = s0 + BOH;
        float* v0 = s1 + BOH;
        float* v1 = v0 + BOH;
        hipMemsetAsync(d_ws, 0, 2 * BOH * sizeof(float), stream);
        hipMemsetAsync(d_out, 0, BOH * sizeof(float), stream);
        const dim3 grid(NIC_F, NBG), blk(256);
        const int sq_blocks = (BB * OO + 255) / 256;

        pass_kernel<0, true><<<grid, blk, 0, stream>>>(u, w, nullptr, nullptr, s0);
        squash_kernel<<<sq_blocks, 256, 0, stream>>>(s0, v0);
        pass_kernel<1, true><<<grid, blk, 0, stream>>>(u, w, v0, nullptr, s1);
        squash_kernel<<<sq_blocks, 256, 0, stream>>>(s1, v1);
        pass_kernel<2, true><<<grid, blk, 0, stream>>>(u, w, v0, v1, out);
        squash_kernel<<<sq_blocks, 256, 0, stream>>>(out, out);
    }
}

// Round 8
// 372.044 us; speedup vs baseline: 1.0840x; 1.0840x over previous
//
#include <hip/hip_runtime.h>

// Problem constants
#define BB 64
#define II 1152
#define OO 32
#define DD 8
#define HH 16
#define BOH (BB * OO * HH)    // 32768
#define WTILE (OO * DD * HH)  // 4096 floats per i

// Shared per-block shape (R5-proven): NBB=16 b/block, NJB=4 b/thread.
#define NBB  16
#define NBG  4
#define NJB  4

// Fallback (R5-exact) decomposition: 512 blocks.
#define IC_F   9
#define NIC_F  128

// Cooperative decomposition: 256 blocks (R7-proven schedulable).
#define IC_C   18
#define NIC_C  64
#define NBLK_C (NIC_C * NBG)   // 256
#define NGRP_C (NBLK_C / 64)   // 4

// ---------------------------------------------------------------------------
// DPP add helper (ctrl must be an ICE -> template param).
// ---------------------------------------------------------------------------
template<int CTRL>
__device__ __forceinline__ float dpp_add(float x)
{
    return x + __int_as_float(__builtin_amdgcn_update_dpp(
            0, __float_as_int(x), CTRL, 0xF, 0xF, false));
}

__device__ __forceinline__ float row_sum16(float x)
{
    x = dpp_add<0x121>(x);   // row_ror:1
    x = dpp_add<0x122>(x);   // row_ror:2
    x = dpp_add<0x124>(x);   // row_ror:4
    x = dpp_add<0x128>(x);   // row_ror:8
    return x;
}

__device__ __forceinline__ float add_xor32(float x)
{
#if __has_builtin(__builtin_amdgcn_permlane32_swap)
    auto r = __builtin_amdgcn_permlane32_swap(
        __float_as_uint(x), __float_as_uint(x), false, false);
    return __uint_as_float(r[0]) + __uint_as_float(r[1]);
#else
    return x + __shfl_xor(x, 32, 64);
#endif
}

__device__ __forceinline__ float add_xor16(float x)
{
#if __has_builtin(__builtin_amdgcn_permlane16_swap)
    auto r = __builtin_amdgcn_permlane16_swap(
        __float_as_uint(x), __float_as_uint(x), false, false);
    return __uint_as_float(r[0]) + __uint_as_float(r[1]);
#else
    return x + __int_as_float(__builtin_amdgcn_ds_swizzle(__float_as_int(x), 0x401F));
#endif
}

// ---------------------------------------------------------------------------
// 5-bit XOR swizzle within one 4096-float W tile (involution; 16-B groups
// contiguous; read-side bank histogram uniform 8/bank).
// ---------------------------------------------------------------------------
__device__ __forceinline__ int wswz(int f) { return f ^ (((f >> 7) & 31) << 2); }

// Stage one 16 KB W tile global->LDS via DMA. 4 wave-instructions (vmcnt +4).
__device__ __forceinline__ void stage_w_tile(const float* __restrict__ wg,
                                             float* __restrict__ wn, int tid)
{
    #pragma unroll
    for (int j = 0; j < 4; j++) {
        const int P = (tid + j * 256) * 4;
        const int g = wswz(P);
        __builtin_amdgcn_global_load_lds(
            (const __attribute__((address_space(1))) void*)(wg + g),
            (__attribute__((address_space(3))) void*)(wn + P),
            16, 0, 0);
    }
}

// ---------------------------------------------------------------------------
// Two-level grid barrier (R7-proven correct). Monotonic per-phase targets;
// system-scope fences for cross-XCD visibility of part/v.
// ---------------------------------------------------------------------------
__device__ __forceinline__ void gbar(unsigned* __restrict__ bar, int phase, int bi)
{
    __syncthreads();
    if (threadIdx.x == 0) {
        __threadfence_system();
        unsigned* grp    = bar + (bi >> 6);
        unsigned* master = bar + 8;
        unsigned* gen    = bar + 9;
        const unsigned a = __hip_atomic_fetch_add(grp, 1u, __ATOMIC_ACQ_REL,
                                                  __HIP_MEMORY_SCOPE_AGENT) + 1;
        if (a == (unsigned)((phase + 1) * 64)) {
            const unsigned m = __hip_atomic_fetch_add(master, 1u, __ATOMIC_ACQ_REL,
                                                      __HIP_MEMORY_SCOPE_AGENT) + 1;
            if (m == (unsigned)((phase + 1) * NGRP_C)) {
                __hip_atomic_store(gen, (unsigned)(phase + 1), __ATOMIC_RELEASE,
                                   __HIP_MEMORY_SCOPE_AGENT);
            }
        }
        while (__hip_atomic_load(gen, __ATOMIC_ACQUIRE,
                                 __HIP_MEMORY_SCOPE_AGENT) < (unsigned)(phase + 1)) {
            __builtin_amdgcn_s_sleep(2);
        }
        __threadfence_system();
    }
    __syncthreads();
}

// ---------------------------------------------------------------------------
// Persistent cooperative kernel, R8: deep-pipelined pass loop.
// R7 counters (331 us, VALUBusy 7.9%, HBM 2.3%, FETCH 26 MB) showed ~85%
// stall: per-iteration vmcnt(0) drain at 1 block/CU = 15k cyc/iter. Fix is
// T3/T4: 4-deep W ring + counted vmcnt (12/8/4/0) + raw s_barrier; never
// drain in steady state. u staged to LDS once (pass-0 prologue) so the
// in-loop vmcnt stream contains ONLY W DMAs; vsum regs drained before any
// W issue so compiler waits can't hit the pipeline mid-loop.
// ---------------------------------------------------------------------------
__global__ __launch_bounds__(256)
void routing_kernel(const float* __restrict__ u, const float* __restrict__ w,
                    float* __restrict__ part, float* __restrict__ v0,
                    float* __restrict__ v1, float* __restrict__ out,
                    unsigned* __restrict__ bar)
{
    __shared__ __align__(16) float Wsh[4][WTILE];          // 64 KB ring
    __shared__ __align__(16) float uLDS[NBB * IC_C * DD];  // 9.2 KB
    __shared__ float4 red[8][32];                          // 4 KB

    const int tid   = threadIdx.x;
    const int o     = tid & 31;
    const int hh    = (tid >> 5) & 1;
    const int bq    = tid >> 6;
    const int bx    = blockIdx.x;          // i-chunk (0..63)
    const int by    = blockIdx.y;          // b-group (0..3)
    const int bi    = by * NIC_C + bx;     // 0..255
    const int bbase = by * NBB;
    const int i0    = bx * IC_C;
    const int hofs  = hh * 8;
    const int swm   = o << 2;
    const int orow  = o * (DD * HH);

    int phase = 0;

    for (int p = 0; p < 3; ++p) {
        // ---- pass-0 only: stage u slab into LDS via DMA (reused all passes)
        if (p == 0) {
            #pragma unroll
            for (int k = 0; k < 9; k++) {               // 2304 floats / 256 thr
                const int e = tid + k * 256;
                const int b = e / (IC_C * DD);          // /144
                const int r = e - b * (IC_C * DD);
                __builtin_amdgcn_global_load_lds(
                    (const __attribute__((address_space(1))) void*)
                        (u + (size_t)(bbase + b) * (II * DD) + (size_t)i0 * DD + r),
                    (__attribute__((address_space(3))) void*)(uLDS + e),
                    4, 0, 0);
            }
        }

        // ---- vsum in regs; DRAIN before any W DMA so no compiler wait can
        //      land mid-pipeline (its value-waits resolve here).
        float vsum[NJB][8];
        if (p >= 1) {
            #pragma unroll
            for (int jb = 0; jb < NJB; jb++) {
                const int b = bbase + bq * NJB + jb;
                const float* pp = v0 + ((b * OO + o) * HH + hofs);
                float4 a = *(const float4*)pp;
                float4 c = *(const float4*)(pp + 4);
                vsum[jb][0] = a.x; vsum[jb][1] = a.y; vsum[jb][2] = a.z; vsum[jb][3] = a.w;
                vsum[jb][4] = c.x; vsum[jb][5] = c.y; vsum[jb][6] = c.z; vsum[jb][7] = c.w;
                if (p == 2) {
                    const float* q = v1 + ((b * OO + o) * HH + hofs);
                    float4 a2 = *(const float4*)q;
                    float4 c2 = *(const float4*)(q + 4);
                    vsum[jb][0] += a2.x; vsum[jb][1] += a2.y; vsum[jb][2] += a2.z; vsum[jb][3] += a2.w;
                    vsum[jb][4] += c2.x; vsum[jb][5] += c2.y; vsum[jb][6] += c2.z; vsum[jb][7] += c2.w;
                }
            }
            asm volatile("s_waitcnt vmcnt(0)" ::: "memory");
            __builtin_amdgcn_sched_barrier(0);
        }

        // ---- prologue: issue W tiles 0..2 (12 wave-loads in flight) ----
        #pragma unroll
        for (int t = 0; t < 3; t++)
            stage_w_tile(w + (size_t)(i0 + t) * WTILE, Wsh[t], tid);

        if (p == 0) __syncthreads();   // one-time full drain: u + W0..2 landed

        float sacc[NJB][8];
        #pragma unroll
        for (int jb = 0; jb < NJB; jb++)
            #pragma unroll
            for (int h2 = 0; h2 < 8; h2++) sacc[jb][h2] = 0.f;

        // ---- deep-pipelined K-loop: raw barrier + counted vmcnt ----
        for (int ii = 0; ii < IC_C; ii++) {
            __builtin_amdgcn_sched_barrier(0);
            __builtin_amdgcn_s_barrier();        // ring safety: skew < 1 iter
            __builtin_amdgcn_sched_barrier(0);

            if (ii + 3 < IC_C)
                stage_w_tile(w + (size_t)(i0 + ii + 3) * WTILE, Wsh[(ii + 3) & 3], tid);

            const int nah = IC_C - 1 - ii;       // tiles still ahead
            if (nah >= 3)      asm volatile("s_waitcnt vmcnt(12)" ::: "memory");
            else if (nah == 2) asm volatile("s_waitcnt vmcnt(8)"  ::: "memory");
            else if (nah == 1) asm volatile("s_waitcnt vmcnt(4)"  ::: "memory");
            else               asm volatile("s_waitcnt vmcnt(0)"  ::: "memory");
            __builtin_amdgcn_sched_barrier(0);

            const float* wcur = Wsh[ii & 3];

            // u from LDS: wave-uniform address -> broadcast (no conflicts).
            float us[NJB][8];
            #pragma unroll
            for (int jb = 0; jb < NJB; jb++) {
                const float* ub = uLDS + (bq * NJB + jb) * (IC_C * DD) + ii * DD;
                float4 a = *(const float4*)ub;
                float4 c = *(const float4*)(ub + 4);
                us[jb][0] = a.x; us[jb][1] = a.y; us[jb][2] = a.z; us[jb][3] = a.w;
                us[jb][4] = c.x; us[jb][5] = c.y; us[jb][6] = c.z; us[jb][7] = c.w;
            }

            float uh[NJB][8];
            #pragma unroll
            for (int jb = 0; jb < NJB; jb++)
                #pragma unroll
                for (int h2 = 0; h2 < 8; h2++) uh[jb][h2] = 0.f;
            #pragma unroll
            for (int d = 0; d < DD; d++) {
                const int ba  = (d * HH + hofs    ) ^ swm;
                const int bb2 = (d * HH + hofs + 4) ^ swm;
                float4 wa = *(const float4*)&wcur[orow + ba];
                float4 wb = *(const float4*)&wcur[orow + bb2];
                const float wv[8] = {wa.x, wa.y, wa.z, wa.w, wb.x, wb.y, wb.z, wb.w};
                #pragma unroll
                for (int jb = 0; jb < NJB; jb++)
                    #pragma unroll
                    for (int h2 = 0; h2 < 8; h2++)
                        uh[jb][h2] = fmaf(us[jb][d], wv[h2], uh[jb][h2]);
            }

            float cc[NJB];
            if (p == 0) {
                #pragma unroll
                for (int jb = 0; jb < NJB; jb++) cc[jb] = 1.0f / 32.0f;
            } else {
                #pragma unroll
                for (int jb = 0; jb < NJB; jb++) {
                    float lg = 0.f;
                    #pragma unroll
                    for (int h2 = 0; h2 < 8; h2++)
                        lg = fmaf(vsum[jb][h2], uh[jb][h2], lg);
                    lg = add_xor32(lg);
                    const float e = __expf(lg);
                    const float se = add_xor16(row_sum16(e));
                    cc[jb] = __fdividef(e, se);
                }
            }

            #pragma unroll
            for (int jb = 0; jb < NJB; jb++)
                #pragma unroll
                for (int h2 = 0; h2 < 8; h2++)
                    sacc[jb][h2] = fmaf(cc[jb], uh[jb][h2], sacc[jb][h2]);
        }

        // ---- emit partial slab ----
        #pragma unroll
        for (int jb = 0; jb < NJB; jb++) {
            const int b = bbase + bq * NJB + jb;
            float* pp = part + ((size_t)bx * BB + b) * (OO * HH) + o * HH + hofs;
            *(float4*)pp       = make_float4(sacc[jb][0], sacc[jb][1], sacc[jb][2], sacc[jb][3]);
            *(float4*)(pp + 4) = make_float4(sacc[jb][4], sacc[jb][5], sacc[jb][6], sacc[jb][7]);
        }

        gbar(bar, phase++, bi);   // partials visible device-wide

        // ---- reduce + squash: 256 blocks x 32 t4-slices, 64 chunks ----
        {
            float* vt = (p == 0) ? v0 : (p == 1) ? v1 : out;
            const int t4l = tid & 31;
            const int icp = tid >> 5;
            const int t4  = bi * 32 + t4l;

            const float4* pr = (const float4*)part + t4;
            float4 acc = make_float4(0.f, 0.f, 0.f, 0.f);
            #pragma unroll
            for (int k = 0; k < 8; k++) {
                float4 x = pr[(size_t)(icp * 8 + k) * (BOH / 4)];
                acc.x += x.x; acc.y += x.y; acc.z += x.z; acc.w += x.w;
            }
            red[icp][t4l] = acc;
            __syncthreads();

            if (tid < 32) {
                float4 a = red[0][t4l];
                #pragma unroll
                for (int j = 1; j < 8; j++) {
                    float4 x = red[j][t4l];
                    a.x += x.x; a.y += x.y; a.z += x.z; a.w += x.w;
                }
                float sq = a.x * a.x + a.y * a.y + a.z * a.z + a.w * a.w;
                sq = dpp_add<0xB1>(sq);
                sq = dpp_add<0x4E>(sq);
                const float scale = (sq / (1.f + sq)) * rsqrtf(sq + 1e-8f);
                a.x *= scale; a.y *= scale; a.z *= scale; a.w *= scale;
                ((float4*)vt)[t4] = a;
            }
        }

        if (p < 2) gbar(bar, phase++, bi);   // v_p visible device-wide
    }
}

// ---------------------------------------------------------------------------
// Fallback: R5-exact 6-dispatch path (proven 137 us).
// ---------------------------------------------------------------------------
template<int PASS, bool ATOMIC>
__global__ __launch_bounds__(256)
void pass_kernel(const float* __restrict__ u, const float* __restrict__ w,
                 const float* __restrict__ pv0, const float* __restrict__ pv1,
                 float* __restrict__ out)
{
    __shared__ __align__(16) float Wsh[2][WTILE];

    const int tid   = threadIdx.x;
    const int o     = tid & 31;
    const int hh    = (tid >> 5) & 1;
    const int bq    = tid >> 6;
    const int bbase = blockIdx.y * NBB;
    const int i0    = blockIdx.x * IC_F;
    const int hofs  = hh * 8;
    const int swm   = o << 2;
    const int orow  = o * (DD * HH);

    stage_w_tile(w + (size_t)i0 * WTILE, Wsh[0], tid);

    float vsum[NJB][8];
    if (PASS >= 1) {
        #pragma unroll
        for (int jb = 0; jb < NJB; jb++) {
            const int b = bbase + bq * NJB + jb;
            const float* p = pv0 + ((b * OO + o) * HH + hofs);
            float4 a = *(const float4*)p;
            float4 c = *(const float4*)(p + 4);
            vsum[jb][0] = a.x; vsum[jb][1] = a.y; vsum[jb][2] = a.z; vsum[jb][3] = a.w;
            vsum[jb][4] = c.x; vsum[jb][5] = c.y; vsum[jb][6] = c.z; vsum[jb][7] = c.w;
            if (PASS == 2) {
                const float* q = pv1 + ((b * OO + o) * HH + hofs);
                float4 a2 = *(const float4*)q;
                float4 c2 = *(const float4*)(q + 4);
                vsum[jb][0] += a2.x; vsum[jb][1] += a2.y; vsum[jb][2] += a2.z; vsum[jb][3] += a2.w;
                vsum[jb][4] += c2.x; vsum[jb][5] += c2.y; vsum[jb][6] += c2.z; vsum[jb][7] += c2.w;
            }
        }
    }

    float sacc[NJB][8];
    #pragma unroll
    for (int jb = 0; jb < NJB; jb++)
        #pragma unroll
        for (int h2 = 0; h2 < 8; h2++) sacc[jb][h2] = 0.f;

    __syncthreads();

    for (int ii = 0; ii < IC_F; ii++) {
        const float* wcur = Wsh[ii & 1];
        if (ii + 1 < IC_F)
            stage_w_tile(w + (size_t)(i0 + ii + 1) * WTILE, Wsh[(ii + 1) & 1], tid);

        float us[NJB][8];
        #pragma unroll
        for (int jb = 0; jb < NJB; jb++) {
            const float* ub = u + ((size_t)(bbase + bq * NJB + jb) * II + (i0 + ii)) * DD;
            float4 a = *(const float4*)ub;
            float4 c = *(const float4*)(ub + 4);
            us[jb][0] = a.x; us[jb][1] = a.y; us[jb][2] = a.z; us[jb][3] = a.w;
            us[jb][4] = c.x; us[jb][5] = c.y; us[jb][6] = c.z; us[jb][7] = c.w;
        }

        float uh[NJB][8];
        #pragma unroll
        for (int jb = 0; jb < NJB; jb++)
            #pragma unroll
            for (int h2 = 0; h2 < 8; h2++) uh[jb][h2] = 0.f;
        #pragma unroll
        for (int d = 0; d < DD; d++) {
            const int ba  = (d * HH + hofs    ) ^ swm;
            const int bb2 = (d * HH + hofs + 4) ^ swm;
            float4 wa = *(const float4*)&wcur[orow + ba];
            float4 wb = *(const float4*)&wcur[orow + bb2];
            const float wv[8] = {wa.x, wa.y, wa.z, wa.w, wb.x, wb.y, wb.z, wb.w};
            #pragma unroll
            for (int jb = 0; jb < NJB; jb++)
                #pragma unroll
                for (int h2 = 0; h2 < 8; h2++)
                    uh[jb][h2] = fmaf(us[jb][d], wv[h2], uh[jb][h2]);
        }

        float cc[NJB];
        if (PASS == 0) {
            #pragma unroll
            for (int jb = 0; jb < NJB; jb++) cc[jb] = 1.0f / 32.0f;
        } else {
            #pragma unroll
            for (int jb = 0; jb < NJB; jb++) {
                float lg = 0.f;
                #pragma unroll
                for (int h2 = 0; h2 < 8; h2++)
                    lg = fmaf(vsum[jb][h2], uh[jb][h2], lg);
                lg = add_xor32(lg);
                const float e = __expf(lg);
                const float se = add_xor16(row_sum16(e));
                cc[jb] = __fdividef(e, se);
            }
        }

        #pragma unroll
        for (int jb = 0; jb < NJB; jb++)
            #pragma unroll
            for (int h2 = 0; h2 < 8; h2++)
                sacc[jb][h2] = fmaf(cc[jb], uh[jb][h2], sacc[jb][h2]);

        __syncthreads();
    }

    #pragma unroll
    for (int jb = 0; jb < NJB; jb++) {
        const int b = bbase + bq * NJB + jb;
        if (ATOMIC) {
            float* p = out + ((b * OO + o) * HH + hofs);
            #pragma unroll
            for (int h2 = 0; h2 < 8; h2++) atomicAdd(p + h2, sacc[jb][h2]);
        } else {
            float* p = out + ((size_t)blockIdx.x * BB + b) * (OO * HH) + o * HH + hofs;
            *(float4*)p       = make_float4(sacc[jb][0], sacc[jb][1], sacc[jb][2], sacc[jb][3]);
            *(float4*)(p + 4) = make_float4(sacc[jb][4], sacc[jb][5], sacc[jb][6], sacc[jb][7]);
        }
    }
}

__global__ __launch_bounds__(256)
void reduce_squash_wide_kernel(const float* __restrict__ part, float* __restrict__ v)
{
    const int t4l = threadIdx.x & 31;
    const int icp = threadIdx.x >> 5;
    const int t4  = blockIdx.x * 32 + t4l;

    const float4* p = (const float4*)part + t4;
    float4 acc = make_float4(0.f, 0.f, 0.f, 0.f);
    #pragma unroll
    for (int k = 0; k < NIC_F / 8; k++) {
        float4 x = p[(size_t)(icp * (NIC_F / 8) + k) * (BOH / 4)];
        acc.x += x.x; acc.y += x.y; acc.z += x.z; acc.w += x.w;
    }

    __shared__ float4 red[8][32];
    red[icp][t4l] = acc;
    __syncthreads();

    if (threadIdx.x < 32) {
        float4 a = red[0][t4l];
        #pragma unroll
        for (int j = 1; j < 8; j++) {
            float4 x = red[j][t4l];
            a.x += x.x; a.y += x.y; a.z += x.z; a.w += x.w;
        }
        float sq = a.x * a.x + a.y * a.y + a.z * a.z + a.w * a.w;
        sq = dpp_add<0xB1>(sq);
        sq = dpp_add<0x4E>(sq);
        const float scale = (sq / (1.f + sq)) * rsqrtf(sq + 1e-8f);
        a.x *= scale; a.y *= scale; a.z *= scale; a.w *= scale;
        ((float4*)v)[t4] = a;
    }
}

__global__ __launch_bounds__(256)
void squash_kernel(const float* __restrict__ s, float* __restrict__ v)
{
    const int t = blockIdx.x * blockDim.x + threadIdx.x;
    if (t >= BB * OO) return;
    const float4* sp = (const float4*)(s + t * HH);
    float4 a = sp[0], b = sp[1], c = sp[2], d = sp[3];
    float sq = a.x*a.x + a.y*a.y + a.z*a.z + a.w*a.w
             + b.x*b.x + b.y*b.y + b.z*b.z + b.w*b.w
             + c.x*c.x + c.y*c.y + c.z*c.z + c.w*c.w
             + d.x*d.x + d.y*d.y + d.z*d.z + d.w*d.w;
    const float scale = (sq / (1.f + sq)) * rsqrtf(sq + 1e-8f);
    a.x *= scale; a.y *= scale; a.z *= scale; a.w *= scale;
    b.x *= scale; b.y *= scale; b.z *= scale; b.w *= scale;
    c.x *= scale; c.y *= scale; c.z *= scale; c.w *= scale;
    d.x *= scale; d.y *= scale; d.z *= scale; d.w *= scale;
    float4* vp = (float4*)(v + t * HH);
    vp[0] = a; vp[1] = b; vp[2] = c; vp[3] = d;
}

extern "C" void kernel_launch(void* const* d_in, const int* in_sizes, int n_in,
                              void* d_out, int out_size, void* d_ws, size_t ws_size,
                              hipStream_t stream)
{
    (void)in_sizes; (void)n_in; (void)out_size;
    const float* u = (const float*)d_in[0];
    const float* w = (const float*)d_in[1];
    float* out = (float*)d_out;

    const size_t partN = (size_t)NIC_F * BOH;
    const size_t need  = (partN + 2 * BOH + 64) * sizeof(float);   // ~17 MB

    if (ws_size >= need) {
        float* part   = (float*)d_ws;
        float* v0     = part + partN;
        float* v1     = v0 + BOH;
        unsigned* bar = (unsigned*)(v1 + BOH);

        bool done = false;
        int dev = 0, coop = 0;
        if (hipGetDevice(&dev) == hipSuccess)
            (void)hipDeviceGetAttribute(&coop, hipDeviceAttributeCooperativeLaunch, dev);
        if (coop) {
            hipMemsetAsync(bar, 0, 16 * sizeof(unsigned), stream);
            void* args[] = {
                (void*)&u, (void*)&w, (void*)&part, (void*)&v0,
                (void*)&v1, (void*)&out, (void*)&bar
            };
            hipError_t e = hipLaunchCooperativeKernel(
                reinterpret_cast<void*>(routing_kernel),
                dim3(NIC_C, NBG), dim3(256), args, 0, stream);
            if (e == hipSuccess) done = true;
            else (void)hipGetLastError();
        }

        if (!done) {
            const dim3 grid(NIC_F, NBG), blk(256);
            const int rblocks = BOH / 4 / 32;   // 256

            pass_kernel<0, false><<<grid, blk, 0, stream>>>(u, w, nullptr, nullptr, part);
            reduce_squash_wide_kernel<<<rblocks, 256, 0, stream>>>(part, v0);
            pass_kernel<1, false><<<grid, blk, 0, stream>>>(u, w, v0, nullptr, part);
            reduce_squash_wide_kernel<<<rblocks, 256, 0, stream>>>(part, v1);
            pass_kernel<2, false><<<grid, blk, 0, stream>>>(u, w, v0, v1, part);
            reduce_squash_wide_kernel<<<rblocks, 256, 0, stream>>>(part, out);
        }
    } else {
        float* s0 = (float*)d_ws;
        float* s1 = s0 + BOH;
        float* v0 = s1 + BOH;
        float* v1 = v0 + BOH;
        hipMemsetAsync(d_ws, 0, 2 * BOH * sizeof(float), stream);
        hipMemsetAsync(d_out, 0, BOH * sizeof(float), stream);
        const dim3 grid(NIC_F, NBG), blk(256);
        const int sq_blocks = (BB * OO + 255) / 256;

        pass_kernel<0, true><<<grid, blk, 0, stream>>>(u, w, nullptr, nullptr, s0);
        squash_kernel<<<sq_blocks, 256, 0, stream>>>(s0, v0);
        pass_kernel<1, true><<<grid, blk, 0, stream>>>(u, w, v0, nullptr, s1);
        squash_kernel<<<sq_blocks, 256, 0, stream>>>(s1, v1);
        pass_kernel<2, true><<<grid, blk, 0, stream>>>(u, w, v0, v1, out);
        squash_kernel<<<sq_blocks, 256, 0, stream>>>(out, out);
    }
}

// Round 9
// 213.842 us; speedup vs baseline: 1.8859x; 1.7398x over previous
//
#include <hip/hip_runtime.h>

// Problem constants
#define BB 64
#define II 1152
#define OO 32
#define DD 8
#define HH 16
#define BOH (BB * OO * HH)    // 32768
#define WTILE (OO * DD * HH)  // 4096 floats per i

// R5-exact decomposition: NIC * IC == II; grid (NIC, NBG) = 512 blocks.
#define IC   9
#define NIC  128
#define NBB  16    // b per block
#define NBG  4     // b-groups (NBG * NBB == BB)
#define NJB  4     // b per thread

// ---------------------------------------------------------------------------
// DPP add helper (ctrl must be an ICE -> template param).
// ---------------------------------------------------------------------------
template<int CTRL>
__device__ __forceinline__ float dpp_add(float x)
{
    return x + __int_as_float(__builtin_amdgcn_update_dpp(
            0, __float_as_int(x), CTRL, 0xF, 0xF, false));
}

// Sum over each 16-lane row, result in every lane of the row (VALU only).
__device__ __forceinline__ float row_sum16(float x)
{
    x = dpp_add<0x121>(x);   // row_ror:1
    x = dpp_add<0x122>(x);   // row_ror:2
    x = dpp_add<0x124>(x);   // row_ror:4
    x = dpp_add<0x128>(x);   // row_ror:8
    return x;
}

// lane l gets x[l] + x[l^32] — VALU permlane32_swap.
__device__ __forceinline__ float add_xor32(float x)
{
#if __has_builtin(__builtin_amdgcn_permlane32_swap)
    auto r = __builtin_amdgcn_permlane32_swap(
        __float_as_uint(x), __float_as_uint(x), false, false);
    return __uint_as_float(r[0]) + __uint_as_float(r[1]);
#else
    return x + __shfl_xor(x, 32, 64);
#endif
}

// lane l gets x[l] + x[l^16] — VALU permlane16_swap.
__device__ __forceinline__ float add_xor16(float x)
{
#if __has_builtin(__builtin_amdgcn_permlane16_swap)
    auto r = __builtin_amdgcn_permlane16_swap(
        __float_as_uint(x), __float_as_uint(x), false, false);
    return __uint_as_float(r[0]) + __uint_as_float(r[1]);
#else
    return x + __int_as_float(__builtin_amdgcn_ds_swizzle(__float_as_int(x), 0x401F));
#endif
}

// ---------------------------------------------------------------------------
// Pass kernel, R9: NO LDS AT ALL. Evidence table R0..R8: every variant that
// stages W into LDS costs ~40 us/pass regardless of staging mechanism
// (ds_write vs DMA), sync discipline (drain / barrier-free / counted vmcnt),
// or occupancy — the invariant is the 288 KB/CU/pass LDS fill itself.
// Here each thread reads its fixed W slice (o,hh) DIRECTLY from global:
// per d, the wave's 64 lanes cover exactly 32 full 64-B cache lines (perfect
// line utilization); the 4 same-XCD sibling blocks (by=0..3 share bx) hit L2.
// 16 independent loads/thread/iter + 8 waves/CU hide the L2 latency; no
// barriers anywhere in the loop.
// Grid (NIC, NBG) = 512 blocks x 256 thr; tid = o + 32*hh + 64*bq.
// Logits are linear in v -> vsum (= v0 [+ v1]) replaces the logits array;
// PASS 0 has uniform coupling 1/32. Softmax pure-VALU (DPP + permlane).
// ---------------------------------------------------------------------------
template<int PASS, bool ATOMIC>
__global__ __launch_bounds__(256)
void pass_kernel(const float* __restrict__ u, const float* __restrict__ w,
                 const float* __restrict__ pv0, const float* __restrict__ pv1,
                 float* __restrict__ out)
{
    const int tid   = threadIdx.x;
    const int o     = tid & 31;
    const int hh    = (tid >> 5) & 1;
    const int bq    = tid >> 6;           // 0..3
    const int bbase = blockIdx.y * NBB;
    const int i0    = blockIdx.x * IC;
    const int hofs  = hh * 8;

    // This thread's W slice base: w[i][o][d][hofs..hofs+7].
    const float* wbase = w + (size_t)i0 * WTILE + o * (DD * HH) + hofs;

    // vsum = sum of previous v's (constant over i).
    float vsum[NJB][8];
    if (PASS >= 1) {
        #pragma unroll
        for (int jb = 0; jb < NJB; jb++) {
            const int b = bbase + bq * NJB + jb;
            const float* p = pv0 + ((b * OO + o) * HH + hofs);
            float4 a = *(const float4*)p;
            float4 c = *(const float4*)(p + 4);
            vsum[jb][0] = a.x; vsum[jb][1] = a.y; vsum[jb][2] = a.z; vsum[jb][3] = a.w;
            vsum[jb][4] = c.x; vsum[jb][5] = c.y; vsum[jb][6] = c.z; vsum[jb][7] = c.w;
            if (PASS == 2) {
                const float* q = pv1 + ((b * OO + o) * HH + hofs);
                float4 a2 = *(const float4*)q;
                float4 c2 = *(const float4*)(q + 4);
                vsum[jb][0] += a2.x; vsum[jb][1] += a2.y; vsum[jb][2] += a2.z; vsum[jb][3] += a2.w;
                vsum[jb][4] += c2.x; vsum[jb][5] += c2.y; vsum[jb][6] += c2.z; vsum[jb][7] += c2.w;
            }
        }
    }

    float sacc[NJB][8];
    #pragma unroll
    for (int jb = 0; jb < NJB; jb++)
        #pragma unroll
        for (int h2 = 0; h2 < 8; h2++) sacc[jb][h2] = 0.f;

    for (int ii = 0; ii < IC; ii++) {
        const float* wt = wbase + (size_t)ii * WTILE;

        // u via broadcast global loads: whole wave shares bq -> same address.
        float us[NJB][8];
        #pragma unroll
        for (int jb = 0; jb < NJB; jb++) {
            const float* ub = u + ((size_t)(bbase + bq * NJB + jb) * II + (i0 + ii)) * DD;
            float4 a = *(const float4*)ub;
            float4 c = *(const float4*)(ub + 4);
            us[jb][0] = a.x; us[jb][1] = a.y; us[jb][2] = a.z; us[jb][3] = a.w;
            us[jb][4] = c.x; us[jb][5] = c.y; us[jb][6] = c.z; us[jb][7] = c.w;
        }

        // u_hat[b, i, o, h-half] = sum_d u[b,i,d] * W[i,o,d,h]
        // W read directly from global (L2-hot for 3 of 4 sibling blocks; the
        // 16 loads are independent -> compiler hoists, latency under TLP).
        float uh[NJB][8];
        #pragma unroll
        for (int jb = 0; jb < NJB; jb++)
            #pragma unroll
            for (int h2 = 0; h2 < 8; h2++) uh[jb][h2] = 0.f;
        #pragma unroll
        for (int d = 0; d < DD; d++) {
            float4 wa = *(const float4*)(wt + d * HH);
            float4 wb = *(const float4*)(wt + d * HH + 4);
            const float wv[8] = {wa.x, wa.y, wa.z, wa.w, wb.x, wb.y, wb.z, wb.w};
            #pragma unroll
            for (int jb = 0; jb < NJB; jb++)
                #pragma unroll
                for (int h2 = 0; h2 < 8; h2++)
                    uh[jb][h2] = fmaf(us[jb][d], wv[h2], uh[jb][h2]);
        }

        // coupling: softmax over o of (vsum . u_hat); PASS 0 -> uniform 1/32
        float cc[NJB];
        if (PASS == 0) {
            #pragma unroll
            for (int jb = 0; jb < NJB; jb++) cc[jb] = 1.0f / 32.0f;
        } else {
            #pragma unroll
            for (int jb = 0; jb < NJB; jb++) {
                float lg = 0.f;
                #pragma unroll
                for (int h2 = 0; h2 < 8; h2++)
                    lg = fmaf(vsum[jb][h2], uh[jb][h2], lg);
                lg = add_xor32(lg);                // h-half combine (VALU)
                const float e = __expf(lg);        // |lg| small -> no max-sub
                const float se = add_xor16(row_sum16(e));  // sum over 32 o-lanes
                cc[jb] = __fdividef(e, se);
            }
        }

        #pragma unroll
        for (int jb = 0; jb < NJB; jb++)
            #pragma unroll
            for (int h2 = 0; h2 < 8; h2++)
                sacc[jb][h2] = fmaf(cc[jb], uh[jb][h2], sacc[jb][h2]);
    }

    // emit partial s
    #pragma unroll
    for (int jb = 0; jb < NJB; jb++) {
        const int b = bbase + bq * NJB + jb;
        if (ATOMIC) {
            float* p = out + ((b * OO + o) * HH + hofs);
            #pragma unroll
            for (int h2 = 0; h2 < 8; h2++) atomicAdd(p + h2, sacc[jb][h2]);
        } else {
            // per-chunk slab: fully-covered contiguous lines
            float* p = out + ((size_t)blockIdx.x * BB + b) * (OO * HH) + o * HH + hofs;
            *(float4*)p       = make_float4(sacc[jb][0], sacc[jb][1], sacc[jb][2], sacc[jb][3]);
            *(float4*)(p + 4) = make_float4(sacc[jb][4], sacc[jb][5], sacc[jb][6], sacc[jb][7]);
        }
    }
}

// ---------------------------------------------------------------------------
// Fused reduce-over-chunks + squash (R4-proven): 256 blocks spread the
// 16.8 MB partial read over the whole chip. Block handles 32 consecutive
// float4 elements of [b][o][h]; the 128 chunks split 8-ways (icp), LDS tree
// combines; quad-perm DPP does the h-sum for squash.
// ---------------------------------------------------------------------------
__global__ __launch_bounds__(256)
void reduce_squash_wide_kernel(const float* __restrict__ part, float* __restrict__ v)
{
    const int t4l = threadIdx.x & 31;
    const int icp = threadIdx.x >> 5;
    const int t4  = blockIdx.x * 32 + t4l;

    const float4* p = (const float4*)part + t4;
    float4 acc = make_float4(0.f, 0.f, 0.f, 0.f);
    #pragma unroll
    for (int k = 0; k < NIC / 8; k++) {
        float4 x = p[(size_t)(icp * (NIC / 8) + k) * (BOH / 4)];
        acc.x += x.x; acc.y += x.y; acc.z += x.z; acc.w += x.w;
    }

    __shared__ float4 red[8][32];
    red[icp][t4l] = acc;
    __syncthreads();

    if (threadIdx.x < 32) {
        float4 a = red[0][t4l];
        #pragma unroll
        for (int j = 1; j < 8; j++) {
            float4 x = red[j][t4l];
            a.x += x.x; a.y += x.y; a.z += x.z; a.w += x.w;
        }
        float sq = a.x * a.x + a.y * a.y + a.z * a.z + a.w * a.w;
        sq = dpp_add<0xB1>(sq);   // quad_perm [1,0,3,2]
        sq = dpp_add<0x4E>(sq);   // quad_perm [2,3,0,1]
        const float scale = (sq / (1.f + sq)) * rsqrtf(sq + 1e-8f);
        a.x *= scale; a.y *= scale; a.z *= scale; a.w *= scale;
        ((float4*)v)[t4] = a;
    }
}

// Standalone squash for the atomic tiny-ws fallback.
__global__ __launch_bounds__(256)
void squash_kernel(const float* __restrict__ s, float* __restrict__ v)
{
    const int t = blockIdx.x * blockDim.x + threadIdx.x;
    if (t >= BB * OO) return;
    const float4* sp = (const float4*)(s + t * HH);
    float4 a = sp[0], b = sp[1], c = sp[2], d = sp[3];
    float sq = a.x*a.x + a.y*a.y + a.z*a.z + a.w*a.w
             + b.x*b.x + b.y*b.y + b.z*b.z + b.w*b.w
             + c.x*c.x + c.y*c.y + c.z*c.z + c.w*c.w
             + d.x*d.x + d.y*d.y + d.z*d.z + d.w*d.w;
    const float scale = (sq / (1.f + sq)) * rsqrtf(sq + 1e-8f);
    a.x *= scale; a.y *= scale; a.z *= scale; a.w *= scale;
    b.x *= scale; b.y *= scale; b.z *= scale; b.w *= scale;
    c.x *= scale; c.y *= scale; c.z *= scale; c.w *= scale;
    d.x *= scale; d.y *= scale; d.z *= scale; d.w *= scale;
    float4* vp = (float4*)(v + t * HH);
    vp[0] = a; vp[1] = b; vp[2] = c; vp[3] = d;
}

extern "C" void kernel_launch(void* const* d_in, const int* in_sizes, int n_in,
                              void* d_out, int out_size, void* d_ws, size_t ws_size,
                              hipStream_t stream)
{
    (void)in_sizes; (void)n_in; (void)out_size;
    const float* u = (const float*)d_in[0];
    const float* w = (const float*)d_in[1];
    float* out = (float*)d_out;

    const size_t need = ((size_t)NIC * BOH + 2 * BOH) * sizeof(float);  // ~17 MB
    const dim3 grid(NIC, NBG), blk(256);

    if (ws_size >= need) {
        // 6 dispatches; kernel boundaries are the grid barrier.
        float* part = (float*)d_ws;                 // NIC x BOH partial s
        float* v0   = part + (size_t)NIC * BOH;
        float* v1   = v0 + BOH;
        const int rblocks = BOH / 4 / 32;           // 256 blocks

        pass_kernel<0, false><<<grid, blk, 0, stream>>>(u, w, nullptr, nullptr, part);
        reduce_squash_wide_kernel<<<rblocks, 256, 0, stream>>>(part, v0);
        pass_kernel<1, false><<<grid, blk, 0, stream>>>(u, w, v0, nullptr, part);
        reduce_squash_wide_kernel<<<rblocks, 256, 0, stream>>>(part, v1);
        pass_kernel<2, false><<<grid, blk, 0, stream>>>(u, w, v0, v1, part);
        reduce_squash_wide_kernel<<<rblocks, 256, 0, stream>>>(part, out);
    } else {
        // Tiny-ws fallback: atomic path.
        float* s0 = (float*)d_ws;
        float* s1 = s0 + BOH;
        float* v0 = s1 + BOH;
        float* v1 = v0 + BOH;
        hipMemsetAsync(d_ws, 0, 2 * BOH * sizeof(float), stream);
        hipMemsetAsync(d_out, 0, BOH * sizeof(float), stream);
        const int sq_blocks = (BB * OO + 255) / 256;

        pass_kernel<0, true><<<grid, blk, 0, stream>>>(u, w, nullptr, nullptr, s0);
        squash_kernel<<<sq_blocks, 256, 0, stream>>>(s0, v0);
        pass_kernel<1, true><<<grid, blk, 0, stream>>>(u, w, v0, nullptr, s1);
        squash_kernel<<<sq_blocks, 256, 0, stream>>>(s1, v1);
        pass_kernel<2, true><<<grid, blk, 0, stream>>>(u, w, v0, v1, out);
        squash_kernel<<<sq_blocks, 256, 0, stream>>>(out, out);
    }
}

// Round 10
// 153.236 us; speedup vs baseline: 2.6318x; 1.3955x over previous
//
#include <hip/hip_runtime.h>

// Problem constants
#define BB 64
#define II 1152
#define OO 32
#define DD 8
#define HH 16
#define BOH (BB * OO * HH)    // 32768
#define WTILE (OO * DD * HH)  // 4096 floats per i

// Decomposition: NIC * IC == II.
// R10: NIC=192/IC=6 -> grid (192,4) = 768 blocks = 3 blocks/CU = 12 waves/CU
// (R5's 512 blocks = 2/CU left only 2 waves/SIMD to hide the ~85% latency
// stall; R4's 16-wave test confounded TLP with halved NJB). NJB=4 per-thread
// amortization kept (proven). Slab grows 16.8 -> 25.2 MB (~+3 us traffic).
#define IC   6
#define NIC  192
#define NBB  16    // b per block
#define NBG  4     // b-groups (NBG * NBB == BB)
#define NJB  4     // b per thread

// ---------------------------------------------------------------------------
// DPP add helper (ctrl must be an ICE -> template param).
// ---------------------------------------------------------------------------
template<int CTRL>
__device__ __forceinline__ float dpp_add(float x)
{
    return x + __int_as_float(__builtin_amdgcn_update_dpp(
            0, __float_as_int(x), CTRL, 0xF, 0xF, false));
}

// Sum over each 16-lane row, result in every lane of the row (VALU only).
__device__ __forceinline__ float row_sum16(float x)
{
    x = dpp_add<0x121>(x);   // row_ror:1
    x = dpp_add<0x122>(x);   // row_ror:2
    x = dpp_add<0x124>(x);   // row_ror:4
    x = dpp_add<0x128>(x);   // row_ror:8
    return x;
}

// lane l gets x[l] + x[l^32] — VALU permlane32_swap.
__device__ __forceinline__ float add_xor32(float x)
{
#if __has_builtin(__builtin_amdgcn_permlane32_swap)
    auto r = __builtin_amdgcn_permlane32_swap(
        __float_as_uint(x), __float_as_uint(x), false, false);
    return __uint_as_float(r[0]) + __uint_as_float(r[1]);
#else
    return x + __shfl_xor(x, 32, 64);
#endif
}

// lane l gets x[l] + x[l^16] — VALU permlane16_swap.
__device__ __forceinline__ float add_xor16(float x)
{
#if __has_builtin(__builtin_amdgcn_permlane16_swap)
    auto r = __builtin_amdgcn_permlane16_swap(
        __float_as_uint(x), __float_as_uint(x), false, false);
    return __uint_as_float(r[0]) + __uint_as_float(r[1]);
#else
    return x + __int_as_float(__builtin_amdgcn_ds_swizzle(__float_as_int(x), 0x401F));
#endif
}

// ---------------------------------------------------------------------------
// 5-bit XOR swizzle within one 4096-float W tile (involution; 16-B groups
// contiguous; read-side bank histogram uniform 8/bank -> conflict-free).
// ---------------------------------------------------------------------------
__device__ __forceinline__ int wswz(int f) { return f ^ (((f >> 7) & 31) << 2); }

// Stage one 16 KB W tile global->LDS via DMA (linear dest, pre-swizzled src;
// both-sides-same-involution rule).
__device__ __forceinline__ void stage_w_tile(const float* __restrict__ wg,
                                             float* __restrict__ wn, int tid)
{
    #pragma unroll
    for (int j = 0; j < 4; j++) {
        const int P = (tid + j * 256) * 4;
        const int g = wswz(P);
        __builtin_amdgcn_global_load_lds(
            (const __attribute__((address_space(1))) void*)(wg + g),
            (__attribute__((address_space(3))) void*)(wn + P),
            16, 0, 0);
    }
}

// ---------------------------------------------------------------------------
// Pass kernel (R5-proven body): one routing iteration.
// Grid (NIC, NBG) = 768 blocks x 256 thr; tid = o + 32*hh + 64*bq.
// Logits are linear in v -> vsum (= v0 [+ v1]) replaces the logits array;
// PASS 0 has uniform coupling 1/32.
//  - W staged by global_load_lds DMA into a 2-buffer pipeline.
//  - u via broadcast global loads (wave shares bq -> same address).
//  - softmax pure-VALU (DPP row_ror + permlane swaps).
//  - NJB=4: 8 uh-FMAs amortize one softmax + one staging quantum.
// ---------------------------------------------------------------------------
template<int PASS, bool ATOMIC>
__global__ __launch_bounds__(256)
void pass_kernel(const float* __restrict__ u, const float* __restrict__ w,
                 const float* __restrict__ pv0, const float* __restrict__ pv1,
                 float* __restrict__ out)
{
    __shared__ __align__(16) float Wsh[2][WTILE];   // 2 x 16 KB, linear

    const int tid   = threadIdx.x;
    const int o     = tid & 31;
    const int hh    = (tid >> 5) & 1;
    const int bq    = tid >> 6;           // 0..3
    const int bbase = blockIdx.y * NBB;
    const int i0    = blockIdx.x * IC;
    const int hofs  = hh * 8;
    const int swm   = o << 2;             // read-side XOR (floats), 5-bit
    const int orow  = o * (DD * HH);

    // Kick off DMA for W[i0] immediately (overlaps vsum loads below).
    stage_w_tile(w + (size_t)i0 * WTILE, Wsh[0], tid);

    // vsum = sum of previous v's (constant over i).
    float vsum[NJB][8];
    if (PASS >= 1) {
        #pragma unroll
        for (int jb = 0; jb < NJB; jb++) {
            const int b = bbase + bq * NJB + jb;
            const float* p = pv0 + ((b * OO + o) * HH + hofs);
            float4 a = *(const float4*)p;
            float4 c = *(const float4*)(p + 4);
            vsum[jb][0] = a.x; vsum[jb][1] = a.y; vsum[jb][2] = a.z; vsum[jb][3] = a.w;
            vsum[jb][4] = c.x; vsum[jb][5] = c.y; vsum[jb][6] = c.z; vsum[jb][7] = c.w;
            if (PASS == 2) {
                const float* q = pv1 + ((b * OO + o) * HH + hofs);
                float4 a2 = *(const float4*)q;
                float4 c2 = *(const float4*)(q + 4);
                vsum[jb][0] += a2.x; vsum[jb][1] += a2.y; vsum[jb][2] += a2.z; vsum[jb][3] += a2.w;
                vsum[jb][4] += c2.x; vsum[jb][5] += c2.y; vsum[jb][6] += c2.z; vsum[jb][7] += c2.w;
            }
        }
    }

    float sacc[NJB][8];
    #pragma unroll
    for (int jb = 0; jb < NJB; jb++)
        #pragma unroll
        for (int h2 = 0; h2 < 8; h2++) sacc[jb][h2] = 0.f;

    __syncthreads();   // drains vmcnt(0): Wsh[0] DMA complete

    for (int ii = 0; ii < IC; ii++) {
        const float* wcur = Wsh[ii & 1];

        // Issue next tile's DMA first; it has the whole compute phase to land.
        if (ii + 1 < IC)
            stage_w_tile(w + (size_t)(i0 + ii + 1) * WTILE, Wsh[(ii + 1) & 1], tid);

        // u via broadcast global loads: whole wave shares bq -> same address.
        float us[NJB][8];
        #pragma unroll
        for (int jb = 0; jb < NJB; jb++) {
            const float* ub = u + ((size_t)(bbase + bq * NJB + jb) * II + (i0 + ii)) * DD;
            float4 a = *(const float4*)ub;
            float4 c = *(const float4*)(ub + 4);
            us[jb][0] = a.x; us[jb][1] = a.y; us[jb][2] = a.z; us[jb][3] = a.w;
            us[jb][4] = c.x; us[jb][5] = c.y; us[jb][6] = c.z; us[jb][7] = c.w;
        }

        // u_hat[b, i, o, h-half] = sum_d u[b,i,d] * W[i,o,d,h]
        float uh[NJB][8];
        #pragma unroll
        for (int jb = 0; jb < NJB; jb++)
            #pragma unroll
            for (int h2 = 0; h2 < 8; h2++) uh[jb][h2] = 0.f;
        #pragma unroll
        for (int d = 0; d < DD; d++) {
            const int ba  = (d * HH + hofs    ) ^ swm;   // swizzled read offsets
            const int bb2 = (d * HH + hofs + 4) ^ swm;
            float4 wa = *(const float4*)&wcur[orow + ba];
            float4 wb = *(const float4*)&wcur[orow + bb2];
            const float wv[8] = {wa.x, wa.y, wa.z, wa.w, wb.x, wb.y, wb.z, wb.w};
            #pragma unroll
            for (int jb = 0; jb < NJB; jb++)
                #pragma unroll
                for (int h2 = 0; h2 < 8; h2++)
                    uh[jb][h2] = fmaf(us[jb][d], wv[h2], uh[jb][h2]);
        }

        // coupling: softmax over o of (vsum . u_hat); PASS 0 -> uniform 1/32
        float cc[NJB];
        if (PASS == 0) {
            #pragma unroll
            for (int jb = 0; jb < NJB; jb++) cc[jb] = 1.0f / 32.0f;
        } else {
            #pragma unroll
            for (int jb = 0; jb < NJB; jb++) {
                float lg = 0.f;
                #pragma unroll
                for (int h2 = 0; h2 < 8; h2++)
                    lg = fmaf(vsum[jb][h2], uh[jb][h2], lg);
                lg = add_xor32(lg);                // h-half combine (VALU)
                const float e = __expf(lg);        // |lg| small -> no max-sub
                const float se = add_xor16(row_sum16(e));  // sum over 32 o-lanes
                cc[jb] = __fdividef(e, se);
            }
        }

        #pragma unroll
        for (int jb = 0; jb < NJB; jb++)
            #pragma unroll
            for (int h2 = 0; h2 < 8; h2++)
                sacc[jb][h2] = fmaf(cc[jb], uh[jb][h2], sacc[jb][h2]);

        // barrier drains vmcnt (next tile's DMA) + lgkmcnt (our LDS reads)
        __syncthreads();
    }

    // emit partial s
    #pragma unroll
    for (int jb = 0; jb < NJB; jb++) {
        const int b = bbase + bq * NJB + jb;
        if (ATOMIC) {
            float* p = out + ((b * OO + o) * HH + hofs);
            #pragma unroll
            for (int h2 = 0; h2 < 8; h2++) atomicAdd(p + h2, sacc[jb][h2]);
        } else {
            // per-chunk slab: fully-covered contiguous lines
            float* p = out + ((size_t)blockIdx.x * BB + b) * (OO * HH) + o * HH + hofs;
            *(float4*)p       = make_float4(sacc[jb][0], sacc[jb][1], sacc[jb][2], sacc[jb][3]);
            *(float4*)(p + 4) = make_float4(sacc[jb][4], sacc[jb][5], sacc[jb][6], sacc[jb][7]);
        }
    }
}

// ---------------------------------------------------------------------------
// Fused reduce-over-chunks + squash (R4-proven shape): 256 blocks spread the
// 25.2 MB partial read over the whole chip. Block handles 32 consecutive
// float4 elements of [b][o][h]; the 192 chunks split 8-ways (icp, 24 each),
// LDS tree combines; quad-perm DPP does the h-sum for squash.
// ---------------------------------------------------------------------------
__global__ __launch_bounds__(256)
void reduce_squash_wide_kernel(const float* __restrict__ part, float* __restrict__ v)
{
    const int t4l = threadIdx.x & 31;
    const int icp = threadIdx.x >> 5;
    const int t4  = blockIdx.x * 32 + t4l;

    const float4* p = (const float4*)part + t4;
    float4 acc = make_float4(0.f, 0.f, 0.f, 0.f);
    #pragma unroll
    for (int k = 0; k < NIC / 8; k++) {
        float4 x = p[(size_t)(icp * (NIC / 8) + k) * (BOH / 4)];
        acc.x += x.x; acc.y += x.y; acc.z += x.z; acc.w += x.w;
    }

    __shared__ float4 red[8][32];
    red[icp][t4l] = acc;
    __syncthreads();

    if (threadIdx.x < 32) {
        float4 a = red[0][t4l];
        #pragma unroll
        for (int j = 1; j < 8; j++) {
            float4 x = red[j][t4l];
            a.x += x.x; a.y += x.y; a.z += x.z; a.w += x.w;
        }
        float sq = a.x * a.x + a.y * a.y + a.z * a.z + a.w * a.w;
        sq = dpp_add<0xB1>(sq);   // quad_perm [1,0,3,2]
        sq = dpp_add<0x4E>(sq);   // quad_perm [2,3,0,1]
        const float scale = (sq / (1.f + sq)) * rsqrtf(sq + 1e-8f);
        a.x *= scale; a.y *= scale; a.z *= scale; a.w *= scale;
        ((float4*)v)[t4] = a;
    }
}

// Standalone squash for the atomic tiny-ws fallback.
__global__ __launch_bounds__(256)
void squash_kernel(const float* __restrict__ s, float* __restrict__ v)
{
    const int t = blockIdx.x * blockDim.x + threadIdx.x;
    if (t >= BB * OO) return;
    const float4* sp = (const float4*)(s + t * HH);
    float4 a = sp[0], b = sp[1], c = sp[2], d = sp[3];
    float sq = a.x*a.x + a.y*a.y + a.z*a.z + a.w*a.w
             + b.x*b.x + b.y*b.y + b.z*b.z + b.w*b.w
             + c.x*c.x + c.y*c.y + c.z*c.z + c.w*c.w
             + d.x*d.x + d.y*d.y + d.z*d.z + d.w*d.w;
    const float scale = (sq / (1.f + sq)) * rsqrtf(sq + 1e-8f);
    a.x *= scale; a.y *= scale; a.z *= scale; a.w *= scale;
    b.x *= scale; b.y *= scale; b.z *= scale; b.w *= scale;
    c.x *= scale; c.y *= scale; c.z *= scale; c.w *= scale;
    d.x *= scale; d.y *= scale; d.z *= scale; d.w *= scale;
    float4* vp = (float4*)(v + t * HH);
    vp[0] = a; vp[1] = b; vp[2] = c; vp[3] = d;
}

extern "C" void kernel_launch(void* const* d_in, const int* in_sizes, int n_in,
                              void* d_out, int out_size, void* d_ws, size_t ws_size,
                              hipStream_t stream)
{
    (void)in_sizes; (void)n_in; (void)out_size;
    const float* u = (const float*)d_in[0];
    const float* w = (const float*)d_in[1];
    float* out = (float*)d_out;

    const size_t need = ((size_t)NIC * BOH + 2 * BOH) * sizeof(float);  // ~25.5 MB
    const dim3 grid(NIC, NBG), blk(256);

    if (ws_size >= need) {
        // 6 dispatches; kernel boundaries are the grid barrier.
        float* part = (float*)d_ws;                 // NIC x BOH partial s
        float* v0   = part + (size_t)NIC * BOH;
        float* v1   = v0 + BOH;
        const int rblocks = BOH / 4 / 32;           // 256 blocks

        pass_kernel<0, false><<<grid, blk, 0, stream>>>(u, w, nullptr, nullptr, part);
        reduce_squash_wide_kernel<<<rblocks, 256, 0, stream>>>(part, v0);
        pass_kernel<1, false><<<grid, blk, 0, stream>>>(u, w, v0, nullptr, part);
        reduce_squash_wide_kernel<<<rblocks, 256, 0, stream>>>(part, v1);
        pass_kernel<2, false><<<grid, blk, 0, stream>>>(u, w, v0, v1, part);
        reduce_squash_wide_kernel<<<rblocks, 256, 0, stream>>>(part, out);
    } else {
        // Tiny-ws fallback: atomic path.
        float* s0 = (float*)d_ws;
        float* s1 = s0 + BOH;
        float* v0 = s1 + BOH;
        float* v1 = v0 + BOH;
        hipMemsetAsync(d_ws, 0, 2 * BOH * sizeof(float), stream);
        hipMemsetAsync(d_out, 0, BOH * sizeof(float), stream);
        const int sq_blocks = (BB * OO + 255) / 256;

        pass_kernel<0, true><<<grid, blk, 0, stream>>>(u, w, nullptr, nullptr, s0);
        squash_kernel<<<sq_blocks, 256, 0, stream>>>(s0, v0);
        pass_kernel<1, true><<<grid, blk, 0, stream>>>(u, w, v0, nullptr, s1);
        squash_kernel<<<sq_blocks, 256, 0, stream>>>(s1, v1);
        pass_kernel<2, true><<<grid, blk, 0, stream>>>(u, w, v0, v1, out);
        squash_kernel<<<sq_blocks, 256, 0, stream>>>(out, out);
    }
}

// Round 11
// 130.332 us; speedup vs baseline: 3.0943x; 1.1757x over previous
//
#include <hip/hip_runtime.h>

// Problem constants
#define BB 64
#define II 1152
#define OO 32
#define DD 8
#define HH 16
#define BOH (BB * OO * HH)    // 32768
#define WTILE (OO * DD * HH)  // 4096 floats per i

// Producer / fallback decomposition (R5-exact): NIC * IC == II, 512 blocks.
#define IC   9
#define NIC  128
#define NBB  16    // b per block
#define NBG  4     // b-groups
#define NJB  4     // b per thread

// Fast-pass decomposition: 1024 blocks (4/CU, 16 waves/CU). No LDS/W staging
// -> NJB has no amortization role; smaller NJB buys TLP for free.
#define NBBF 8
#define NBGF 8
#define NJBF 2

typedef _Float16 half8 __attribute__((ext_vector_type(8)));

// u_hat element count (fp16): 75.5 MB
#define UHN ((size_t)BB * II * OO * HH)

// ---------------------------------------------------------------------------
// DPP add helper (ctrl must be an ICE -> template param).
// ---------------------------------------------------------------------------
template<int CTRL>
__device__ __forceinline__ float dpp_add(float x)
{
    return x + __int_as_float(__builtin_amdgcn_update_dpp(
            0, __float_as_int(x), CTRL, 0xF, 0xF, false));
}

// Sum over each 16-lane row, result in every lane of the row (VALU only).
__device__ __forceinline__ float row_sum16(float x)
{
    x = dpp_add<0x121>(x);   // row_ror:1
    x = dpp_add<0x122>(x);   // row_ror:2
    x = dpp_add<0x124>(x);   // row_ror:4
    x = dpp_add<0x128>(x);   // row_ror:8
    return x;
}

// lane l gets x[l] + x[l^32] — VALU permlane32_swap.
__device__ __forceinline__ float add_xor32(float x)
{
#if __has_builtin(__builtin_amdgcn_permlane32_swap)
    auto r = __builtin_amdgcn_permlane32_swap(
        __float_as_uint(x), __float_as_uint(x), false, false);
    return __uint_as_float(r[0]) + __uint_as_float(r[1]);
#else
    return x + __shfl_xor(x, 32, 64);
#endif
}

// lane l gets x[l] + x[l^16] — VALU permlane16_swap.
__device__ __forceinline__ float add_xor16(float x)
{
#if __has_builtin(__builtin_amdgcn_permlane16_swap)
    auto r = __builtin_amdgcn_permlane16_swap(
        __float_as_uint(x), __float_as_uint(x), false, false);
    return __uint_as_float(r[0]) + __uint_as_float(r[1]);
#else
    return x + __int_as_float(__builtin_amdgcn_ds_swizzle(__float_as_int(x), 0x401F));
#endif
}

// ---------------------------------------------------------------------------
// 5-bit XOR swizzle within one 4096-float W tile (involution; 16-B groups
// contiguous; read-side bank histogram uniform 8/bank -> conflict-free).
// ---------------------------------------------------------------------------
__device__ __forceinline__ int wswz(int f) { return f ^ (((f >> 7) & 31) << 2); }

// Stage one 16 KB W tile global->LDS via DMA (linear dest, pre-swizzled src).
__device__ __forceinline__ void stage_w_tile(const float* __restrict__ wg,
                                             float* __restrict__ wn, int tid)
{
    #pragma unroll
    for (int j = 0; j < 4; j++) {
        const int P = (tid + j * 256) * 4;
        const int g = wswz(P);
        __builtin_amdgcn_global_load_lds(
            (const __attribute__((address_space(1))) void*)(wg + g),
            (__attribute__((address_space(3))) void*)(wn + P),
            16, 0, 0);
    }
}

// ---------------------------------------------------------------------------
// Pass kernel (R5-proven body). UHAT=true additionally stores u_hat as fp16
// (wave-contiguous 1 KB rows per (b,i)) for the fast passes to stream.
// Grid (NIC, NBG) = 512 blocks x 256 thr; tid = o + 32*hh + 64*bq.
// ---------------------------------------------------------------------------
template<int PASS, bool ATOMIC, bool UHAT>
__global__ __launch_bounds__(256)
void pass_kernel(const float* __restrict__ u, const float* __restrict__ w,
                 const float* __restrict__ pv0, const float* __restrict__ pv1,
                 float* __restrict__ out, _Float16* __restrict__ uhat)
{
    __shared__ __align__(16) float Wsh[2][WTILE];   // 2 x 16 KB, linear

    const int tid   = threadIdx.x;
    const int o     = tid & 31;
    const int hh    = (tid >> 5) & 1;
    const int bq    = tid >> 6;           // 0..3
    const int bbase = blockIdx.y * NBB;
    const int i0    = blockIdx.x * IC;
    const int hofs  = hh * 8;
    const int swm   = o << 2;             // read-side XOR (floats), 5-bit
    const int orow  = o * (DD * HH);

    stage_w_tile(w + (size_t)i0 * WTILE, Wsh[0], tid);

    float vsum[NJB][8];
    if (PASS >= 1) {
        #pragma unroll
        for (int jb = 0; jb < NJB; jb++) {
            const int b = bbase + bq * NJB + jb;
            const float* p = pv0 + ((b * OO + o) * HH + hofs);
            float4 a = *(const float4*)p;
            float4 c = *(const float4*)(p + 4);
            vsum[jb][0] = a.x; vsum[jb][1] = a.y; vsum[jb][2] = a.z; vsum[jb][3] = a.w;
            vsum[jb][4] = c.x; vsum[jb][5] = c.y; vsum[jb][6] = c.z; vsum[jb][7] = c.w;
            if (PASS == 2) {
                const float* q = pv1 + ((b * OO + o) * HH + hofs);
                float4 a2 = *(const float4*)q;
                float4 c2 = *(const float4*)(q + 4);
                vsum[jb][0] += a2.x; vsum[jb][1] += a2.y; vsum[jb][2] += a2.z; vsum[jb][3] += a2.w;
                vsum[jb][4] += c2.x; vsum[jb][5] += c2.y; vsum[jb][6] += c2.z; vsum[jb][7] += c2.w;
            }
        }
    }

    float sacc[NJB][8];
    #pragma unroll
    for (int jb = 0; jb < NJB; jb++)
        #pragma unroll
        for (int h2 = 0; h2 < 8; h2++) sacc[jb][h2] = 0.f;

    __syncthreads();   // drains vmcnt(0): Wsh[0] DMA complete

    for (int ii = 0; ii < IC; ii++) {
        const float* wcur = Wsh[ii & 1];

        if (ii + 1 < IC)
            stage_w_tile(w + (size_t)(i0 + ii + 1) * WTILE, Wsh[(ii + 1) & 1], tid);

        float us[NJB][8];
        #pragma unroll
        for (int jb = 0; jb < NJB; jb++) {
            const float* ub = u + ((size_t)(bbase + bq * NJB + jb) * II + (i0 + ii)) * DD;
            float4 a = *(const float4*)ub;
            float4 c = *(const float4*)(ub + 4);
            us[jb][0] = a.x; us[jb][1] = a.y; us[jb][2] = a.z; us[jb][3] = a.w;
            us[jb][4] = c.x; us[jb][5] = c.y; us[jb][6] = c.z; us[jb][7] = c.w;
        }

        float uh[NJB][8];
        #pragma unroll
        for (int jb = 0; jb < NJB; jb++)
            #pragma unroll
            for (int h2 = 0; h2 < 8; h2++) uh[jb][h2] = 0.f;
        #pragma unroll
        for (int d = 0; d < DD; d++) {
            const int ba  = (d * HH + hofs    ) ^ swm;
            const int bb2 = (d * HH + hofs + 4) ^ swm;
            float4 wa = *(const float4*)&wcur[orow + ba];
            float4 wb = *(const float4*)&wcur[orow + bb2];
            const float wv[8] = {wa.x, wa.y, wa.z, wa.w, wb.x, wb.y, wb.z, wb.w};
            #pragma unroll
            for (int jb = 0; jb < NJB; jb++)
                #pragma unroll
                for (int h2 = 0; h2 < 8; h2++)
                    uh[jb][h2] = fmaf(us[jb][d], wv[h2], uh[jb][h2]);
        }

        // Store u_hat (fp16) for the streaming passes. Wave writes 4 x 1 KB
        // contiguous rows; stores overlap the next tile's DMA window.
        if (UHAT) {
            #pragma unroll
            for (int jb = 0; jb < NJB; jb++) {
                const int b = bbase + bq * NJB + jb;
                half8 hv;
                #pragma unroll
                for (int h2 = 0; h2 < 8; h2++) hv[h2] = (_Float16)uh[jb][h2];
                *(half8*)(uhat + (((size_t)b * II + (i0 + ii)) * OO + o) * HH + hofs) = hv;
            }
        }

        float cc[NJB];
        if (PASS == 0) {
            #pragma unroll
            for (int jb = 0; jb < NJB; jb++) cc[jb] = 1.0f / 32.0f;
        } else {
            #pragma unroll
            for (int jb = 0; jb < NJB; jb++) {
                float lg = 0.f;
                #pragma unroll
                for (int h2 = 0; h2 < 8; h2++)
                    lg = fmaf(vsum[jb][h2], uh[jb][h2], lg);
                lg = add_xor32(lg);
                const float e = __expf(lg);
                const float se = add_xor16(row_sum16(e));
                cc[jb] = __fdividef(e, se);
            }
        }

        #pragma unroll
        for (int jb = 0; jb < NJB; jb++)
            #pragma unroll
            for (int h2 = 0; h2 < 8; h2++)
                sacc[jb][h2] = fmaf(cc[jb], uh[jb][h2], sacc[jb][h2]);

        __syncthreads();
    }

    #pragma unroll
    for (int jb = 0; jb < NJB; jb++) {
        const int b = bbase + bq * NJB + jb;
        if (ATOMIC) {
            float* p = out + ((b * OO + o) * HH + hofs);
            #pragma unroll
            for (int h2 = 0; h2 < 8; h2++) atomicAdd(p + h2, sacc[jb][h2]);
        } else {
            float* p = out + ((size_t)blockIdx.x * BB + b) * (OO * HH) + o * HH + hofs;
            *(float4*)p       = make_float4(sacc[jb][0], sacc[jb][1], sacc[jb][2], sacc[jb][3]);
            *(float4*)(p + 4) = make_float4(sacc[jb][4], sacc[jb][5], sacc[jb][6], sacc[jb][7]);
        }
    }
}

// ---------------------------------------------------------------------------
// Fast pass (R11): streams precomputed fp16 u_hat. NO u, NO W, NO LDS, NO
// barriers — per thread per iteration: 2 x 16 B contiguous loads + VALU
// softmax. Grid (NIC, NBGF) = 1024 blocks x 256 thr (16 waves/CU).
// tid = o + 32*hh + 64*bq; bq*NJBF+jb covers NBBF=8 b's per block.
// ---------------------------------------------------------------------------
template<int PASS>
__global__ __launch_bounds__(256)
void fast_pass_kernel(const _Float16* __restrict__ uhat,
                      const float* __restrict__ pv0, const float* __restrict__ pv1,
                      float* __restrict__ out)
{
    const int tid   = threadIdx.x;
    const int o     = tid & 31;
    const int hh    = (tid >> 5) & 1;
    const int bq    = tid >> 6;            // 0..3
    const int bbase = blockIdx.y * NBBF;   // 8 b per block
    const int i0    = blockIdx.x * IC;
    const int hofs  = hh * 8;

    float vsum[NJBF][8];
    #pragma unroll
    for (int jb = 0; jb < NJBF; jb++) {
        const int b = bbase + bq * NJBF + jb;
        const float* p = pv0 + ((b * OO + o) * HH + hofs);
        float4 a = *(const float4*)p;
        float4 c = *(const float4*)(p + 4);
        vsum[jb][0] = a.x; vsum[jb][1] = a.y; vsum[jb][2] = a.z; vsum[jb][3] = a.w;
        vsum[jb][4] = c.x; vsum[jb][5] = c.y; vsum[jb][6] = c.z; vsum[jb][7] = c.w;
        if (PASS == 2) {
            const float* q = pv1 + ((b * OO + o) * HH + hofs);
            float4 a2 = *(const float4*)q;
            float4 c2 = *(const float4*)(q + 4);
            vsum[jb][0] += a2.x; vsum[jb][1] += a2.y; vsum[jb][2] += a2.z; vsum[jb][3] += a2.w;
            vsum[jb][4] += c2.x; vsum[jb][5] += c2.y; vsum[jb][6] += c2.z; vsum[jb][7] += c2.w;
        }
    }

    float sacc[NJBF][8];
    #pragma unroll
    for (int jb = 0; jb < NJBF; jb++)
        #pragma unroll
        for (int h2 = 0; h2 < 8; h2++) sacc[jb][h2] = 0.f;

    #pragma unroll
    for (int ii = 0; ii < IC; ii++) {
        #pragma unroll
        for (int jb = 0; jb < NJBF; jb++) {
            const int b = bbase + bq * NJBF + jb;
            const half8 hv = *(const half8*)
                (uhat + (((size_t)b * II + (i0 + ii)) * OO + o) * HH + hofs);
            float uh[8];
            #pragma unroll
            for (int h2 = 0; h2 < 8; h2++) uh[h2] = (float)hv[h2];

            float lg = 0.f;
            #pragma unroll
            for (int h2 = 0; h2 < 8; h2++)
                lg = fmaf(vsum[jb][h2], uh[h2], lg);
            lg = add_xor32(lg);                // h-half combine (VALU)
            const float e = __expf(lg);
            const float se = add_xor16(row_sum16(e));  // sum over 32 o-lanes
            const float cc = __fdividef(e, se);

            #pragma unroll
            for (int h2 = 0; h2 < 8; h2++)
                sacc[jb][h2] = fmaf(cc, uh[h2], sacc[jb][h2]);
        }
    }

    #pragma unroll
    for (int jb = 0; jb < NJBF; jb++) {
        const int b = bbase + bq * NJBF + jb;
        float* p = out + ((size_t)blockIdx.x * BB + b) * (OO * HH) + o * HH + hofs;
        *(float4*)p       = make_float4(sacc[jb][0], sacc[jb][1], sacc[jb][2], sacc[jb][3]);
        *(float4*)(p + 4) = make_float4(sacc[jb][4], sacc[jb][5], sacc[jb][6], sacc[jb][7]);
    }
}

// ---------------------------------------------------------------------------
// Fused reduce-over-chunks + squash (R4-proven): 256 blocks spread the
// 16.8 MB partial read over the whole chip.
// ---------------------------------------------------------------------------
__global__ __launch_bounds__(256)
void reduce_squash_wide_kernel(const float* __restrict__ part, float* __restrict__ v)
{
    const int t4l = threadIdx.x & 31;
    const int icp = threadIdx.x >> 5;
    const int t4  = blockIdx.x * 32 + t4l;

    const float4* p = (const float4*)part + t4;
    float4 acc = make_float4(0.f, 0.f, 0.f, 0.f);
    #pragma unroll
    for (int k = 0; k < NIC / 8; k++) {
        float4 x = p[(size_t)(icp * (NIC / 8) + k) * (BOH / 4)];
        acc.x += x.x; acc.y += x.y; acc.z += x.z; acc.w += x.w;
    }

    __shared__ float4 red[8][32];
    red[icp][t4l] = acc;
    __syncthreads();

    if (threadIdx.x < 32) {
        float4 a = red[0][t4l];
        #pragma unroll
        for (int j = 1; j < 8; j++) {
            float4 x = red[j][t4l];
            a.x += x.x; a.y += x.y; a.z += x.z; a.w += x.w;
        }
        float sq = a.x * a.x + a.y * a.y + a.z * a.z + a.w * a.w;
        sq = dpp_add<0xB1>(sq);   // quad_perm [1,0,3,2]
        sq = dpp_add<0x4E>(sq);   // quad_perm [2,3,0,1]
        const float scale = (sq / (1.f + sq)) * rsqrtf(sq + 1e-8f);
        a.x *= scale; a.y *= scale; a.z *= scale; a.w *= scale;
        ((float4*)v)[t4] = a;
    }
}

// Standalone squash for the atomic tiny-ws fallback.
__global__ __launch_bounds__(256)
void squash_kernel(const float* __restrict__ s, float* __restrict__ v)
{
    const int t = blockIdx.x * blockDim.x + threadIdx.x;
    if (t >= BB * OO) return;
    const float4* sp = (const float4*)(s + t * HH);
    float4 a = sp[0], b = sp[1], c = sp[2], d = sp[3];
    float sq = a.x*a.x + a.y*a.y + a.z*a.z + a.w*a.w
             + b.x*b.x + b.y*b.y + b.z*b.z + b.w*b.w
             + c.x*c.x + c.y*c.y + c.z*c.z + c.w*c.w
             + d.x*d.x + d.y*d.y + d.z*d.z + d.w*d.w;
    const float scale = (sq / (1.f + sq)) * rsqrtf(sq + 1e-8f);
    a.x *= scale; a.y *= scale; a.z *= scale; a.w *= scale;
    b.x *= scale; b.y *= scale; b.z *= scale; b.w *= scale;
    c.x *= scale; c.y *= scale; c.z *= scale; c.w *= scale;
    d.x *= scale; d.y *= scale; d.z *= scale; d.w *= scale;
    float4* vp = (float4*)(v + t * HH);
    vp[0] = a; vp[1] = b; vp[2] = c; vp[3] = d;
}

extern "C" void kernel_launch(void* const* d_in, const int* in_sizes, int n_in,
                              void* d_out, int out_size, void* d_ws, size_t ws_size,
                              hipStream_t stream)
{
    (void)in_sizes; (void)n_in; (void)out_size;
    const float* u = (const float*)d_in[0];
    const float* w = (const float*)d_in[1];
    float* out = (float*)d_out;

    const size_t partN = (size_t)NIC * BOH;
    const size_t need  = (partN + 2 * BOH) * sizeof(float) + UHN * sizeof(_Float16);
    const dim3 blk(256);

    if (ws_size >= need) {
        // 6 dispatches: producer pass 0 (writes fp16 u_hat) + 2 streaming
        // passes + 3 wide reduces.
        float* part     = (float*)d_ws;
        float* v0       = part + partN;
        float* v1       = v0 + BOH;
        _Float16* uhat  = (_Float16*)(v1 + BOH);    // 16-B aligned offset
        const int rblocks = BOH / 4 / 32;           // 256 blocks

        pass_kernel<0, false, true><<<dim3(NIC, NBG), blk, 0, stream>>>(
            u, w, nullptr, nullptr, part, uhat);
        reduce_squash_wide_kernel<<<rblocks, 256, 0, stream>>>(part, v0);
        fast_pass_kernel<1><<<dim3(NIC, NBGF), blk, 0, stream>>>(uhat, v0, nullptr, part);
        reduce_squash_wide_kernel<<<rblocks, 256, 0, stream>>>(part, v1);
        fast_pass_kernel<2><<<dim3(NIC, NBGF), blk, 0, stream>>>(uhat, v0, v1, part);
        reduce_squash_wide_kernel<<<rblocks, 256, 0, stream>>>(part, out);
    } else {
        // Tiny-ws fallback: R5-exact atomic path.
        float* s0 = (float*)d_ws;
        float* s1 = s0 + BOH;
        float* v0 = s1 + BOH;
        float* v1 = v0 + BOH;
        hipMemsetAsync(d_ws, 0, 2 * BOH * sizeof(float), stream);
        hipMemsetAsync(d_out, 0, BOH * sizeof(float), stream);
        const dim3 grid(NIC, NBG);
        const int sq_blocks = (BB * OO + 255) / 256;

        pass_kernel<0, true, false><<<grid, blk, 0, stream>>>(u, w, nullptr, nullptr, s0, nullptr);
        squash_kernel<<<sq_blocks, 256, 0, stream>>>(s0, v0);
        pass_kernel<1, true, false><<<grid, blk, 0, stream>>>(u, w, v0, nullptr, s1, nullptr);
        squash_kernel<<<sq_blocks, 256, 0, stream>>>(s1, v1);
        pass_kernel<2, true, false><<<grid, blk, 0, stream>>>(u, w, v0, v1, out, nullptr);
        squash_kernel<<<sq_blocks, 256, 0, stream>>>(out, out);
    }
}

// Round 12
// 127.247 us; speedup vs baseline: 3.1694x; 1.0242x over previous
//
#include <hip/hip_runtime.h>

// Problem constants
#define BB 64
#define II 1152
#define OO 32
#define DD 8
#define HH 16
#define BOH (BB * OO * HH)    // 32768
#define WTILE (OO * DD * HH)  // 4096 floats per i

// Producer / fallback decomposition (R5-exact): NIC * IC == II, 512 blocks.
#define IC   9
#define NIC  128
#define NBB  16    // b per block
#define NBG  4     // b-groups
#define NJB  4     // b per thread

// Fast-pass decomposition (R12): 1 b per thread, wave owns one (b, i-chunk).
// Grid (NIC, NBGF) = 2048 blocks = 8/CU = 32 waves/CU. Per thread: 9 u_hat
// rows PREFETCHED to registers, then 9 independent softmax chains (ILP).
#define NBBF 4
#define NBGF 16

typedef _Float16 half8 __attribute__((ext_vector_type(8)));

// u_hat element count (fp16): 75.5 MB
#define UHN ((size_t)BB * II * OO * HH)

// ---------------------------------------------------------------------------
// DPP add helper (ctrl must be an ICE -> template param).
// ---------------------------------------------------------------------------
template<int CTRL>
__device__ __forceinline__ float dpp_add(float x)
{
    return x + __int_as_float(__builtin_amdgcn_update_dpp(
            0, __float_as_int(x), CTRL, 0xF, 0xF, false));
}

// Sum over each 16-lane row, result in every lane of the row (VALU only).
__device__ __forceinline__ float row_sum16(float x)
{
    x = dpp_add<0x121>(x);   // row_ror:1
    x = dpp_add<0x122>(x);   // row_ror:2
    x = dpp_add<0x124>(x);   // row_ror:4
    x = dpp_add<0x128>(x);   // row_ror:8
    return x;
}

// lane l gets x[l] + x[l^32] — VALU permlane32_swap.
__device__ __forceinline__ float add_xor32(float x)
{
#if __has_builtin(__builtin_amdgcn_permlane32_swap)
    auto r = __builtin_amdgcn_permlane32_swap(
        __float_as_uint(x), __float_as_uint(x), false, false);
    return __uint_as_float(r[0]) + __uint_as_float(r[1]);
#else
    return x + __shfl_xor(x, 32, 64);
#endif
}

// lane l gets x[l] + x[l^16] — VALU permlane16_swap.
__device__ __forceinline__ float add_xor16(float x)
{
#if __has_builtin(__builtin_amdgcn_permlane16_swap)
    auto r = __builtin_amdgcn_permlane16_swap(
        __float_as_uint(x), __float_as_uint(x), false, false);
    return __uint_as_float(r[0]) + __uint_as_float(r[1]);
#else
    return x + __int_as_float(__builtin_amdgcn_ds_swizzle(__float_as_int(x), 0x401F));
#endif
}

// ---------------------------------------------------------------------------
// 5-bit XOR swizzle within one 4096-float W tile (involution; 16-B groups
// contiguous; read-side bank histogram uniform 8/bank -> conflict-free).
// ---------------------------------------------------------------------------
__device__ __forceinline__ int wswz(int f) { return f ^ (((f >> 7) & 31) << 2); }

// Stage one 16 KB W tile global->LDS via DMA (linear dest, pre-swizzled src).
__device__ __forceinline__ void stage_w_tile(const float* __restrict__ wg,
                                             float* __restrict__ wn, int tid)
{
    #pragma unroll
    for (int j = 0; j < 4; j++) {
        const int P = (tid + j * 256) * 4;
        const int g = wswz(P);
        __builtin_amdgcn_global_load_lds(
            (const __attribute__((address_space(1))) void*)(wg + g),
            (__attribute__((address_space(3))) void*)(wn + P),
            16, 0, 0);
    }
}

// ---------------------------------------------------------------------------
// Producer pass (R5-proven body). UHAT=true additionally stores u_hat as fp16
// (wave-contiguous 1 KB rows per (b,i)) for the fast passes to stream.
// Grid (NIC, NBG) = 512 blocks x 256 thr; tid = o + 32*hh + 64*bq.
// ---------------------------------------------------------------------------
template<int PASS, bool ATOMIC, bool UHAT>
__global__ __launch_bounds__(256)
void pass_kernel(const float* __restrict__ u, const float* __restrict__ w,
                 const float* __restrict__ pv0, const float* __restrict__ pv1,
                 float* __restrict__ out, _Float16* __restrict__ uhat)
{
    __shared__ __align__(16) float Wsh[2][WTILE];   // 2 x 16 KB, linear

    const int tid   = threadIdx.x;
    const int o     = tid & 31;
    const int hh    = (tid >> 5) & 1;
    const int bq    = tid >> 6;           // 0..3
    const int bbase = blockIdx.y * NBB;
    const int i0    = blockIdx.x * IC;
    const int hofs  = hh * 8;
    const int swm   = o << 2;             // read-side XOR (floats), 5-bit
    const int orow  = o * (DD * HH);

    stage_w_tile(w + (size_t)i0 * WTILE, Wsh[0], tid);

    float vsum[NJB][8];
    if (PASS >= 1) {
        #pragma unroll
        for (int jb = 0; jb < NJB; jb++) {
            const int b = bbase + bq * NJB + jb;
            const float* p = pv0 + ((b * OO + o) * HH + hofs);
            float4 a = *(const float4*)p;
            float4 c = *(const float4*)(p + 4);
            vsum[jb][0] = a.x; vsum[jb][1] = a.y; vsum[jb][2] = a.z; vsum[jb][3] = a.w;
            vsum[jb][4] = c.x; vsum[jb][5] = c.y; vsum[jb][6] = c.z; vsum[jb][7] = c.w;
            if (PASS == 2) {
                const float* q = pv1 + ((b * OO + o) * HH + hofs);
                float4 a2 = *(const float4*)q;
                float4 c2 = *(const float4*)(q + 4);
                vsum[jb][0] += a2.x; vsum[jb][1] += a2.y; vsum[jb][2] += a2.z; vsum[jb][3] += a2.w;
                vsum[jb][4] += c2.x; vsum[jb][5] += c2.y; vsum[jb][6] += c2.z; vsum[jb][7] += c2.w;
            }
        }
    }

    float sacc[NJB][8];
    #pragma unroll
    for (int jb = 0; jb < NJB; jb++)
        #pragma unroll
        for (int h2 = 0; h2 < 8; h2++) sacc[jb][h2] = 0.f;

    __syncthreads();   // drains vmcnt(0): Wsh[0] DMA complete

    for (int ii = 0; ii < IC; ii++) {
        const float* wcur = Wsh[ii & 1];

        if (ii + 1 < IC)
            stage_w_tile(w + (size_t)(i0 + ii + 1) * WTILE, Wsh[(ii + 1) & 1], tid);

        float us[NJB][8];
        #pragma unroll
        for (int jb = 0; jb < NJB; jb++) {
            const float* ub = u + ((size_t)(bbase + bq * NJB + jb) * II + (i0 + ii)) * DD;
            float4 a = *(const float4*)ub;
            float4 c = *(const float4*)(ub + 4);
            us[jb][0] = a.x; us[jb][1] = a.y; us[jb][2] = a.z; us[jb][3] = a.w;
            us[jb][4] = c.x; us[jb][5] = c.y; us[jb][6] = c.z; us[jb][7] = c.w;
        }

        float uh[NJB][8];
        #pragma unroll
        for (int jb = 0; jb < NJB; jb++)
            #pragma unroll
            for (int h2 = 0; h2 < 8; h2++) uh[jb][h2] = 0.f;
        #pragma unroll
        for (int d = 0; d < DD; d++) {
            const int ba  = (d * HH + hofs    ) ^ swm;
            const int bb2 = (d * HH + hofs + 4) ^ swm;
            float4 wa = *(const float4*)&wcur[orow + ba];
            float4 wb = *(const float4*)&wcur[orow + bb2];
            const float wv[8] = {wa.x, wa.y, wa.z, wa.w, wb.x, wb.y, wb.z, wb.w};
            #pragma unroll
            for (int jb = 0; jb < NJB; jb++)
                #pragma unroll
                for (int h2 = 0; h2 < 8; h2++)
                    uh[jb][h2] = fmaf(us[jb][d], wv[h2], uh[jb][h2]);
        }

        // Store u_hat (fp16): wave-contiguous 2 KB rows, overlaps next DMA.
        if (UHAT) {
            #pragma unroll
            for (int jb = 0; jb < NJB; jb++) {
                const int b = bbase + bq * NJB + jb;
                half8 hv;
                #pragma unroll
                for (int h2 = 0; h2 < 8; h2++) hv[h2] = (_Float16)uh[jb][h2];
                *(half8*)(uhat + (((size_t)b * II + (i0 + ii)) * OO + o) * HH + hofs) = hv;
            }
        }

        float cc[NJB];
        if (PASS == 0) {
            #pragma unroll
            for (int jb = 0; jb < NJB; jb++) cc[jb] = 1.0f / 32.0f;
        } else {
            #pragma unroll
            for (int jb = 0; jb < NJB; jb++) {
                float lg = 0.f;
                #pragma unroll
                for (int h2 = 0; h2 < 8; h2++)
                    lg = fmaf(vsum[jb][h2], uh[jb][h2], lg);
                lg = add_xor32(lg);
                const float e = __expf(lg);
                const float se = add_xor16(row_sum16(e));
                cc[jb] = __fdividef(e, se);
            }
        }

        #pragma unroll
        for (int jb = 0; jb < NJB; jb++)
            #pragma unroll
            for (int h2 = 0; h2 < 8; h2++)
                sacc[jb][h2] = fmaf(cc[jb], uh[jb][h2], sacc[jb][h2]);

        __syncthreads();
    }

    #pragma unroll
    for (int jb = 0; jb < NJB; jb++) {
        const int b = bbase + bq * NJB + jb;
        if (ATOMIC) {
            float* p = out + ((b * OO + o) * HH + hofs);
            #pragma unroll
            for (int h2 = 0; h2 < 8; h2++) atomicAdd(p + h2, sacc[jb][h2]);
        } else {
            float* p = out + ((size_t)blockIdx.x * BB + b) * (OO * HH) + o * HH + hofs;
            *(float4*)p       = make_float4(sacc[jb][0], sacc[jb][1], sacc[jb][2], sacc[jb][3]);
            *(float4*)(p + 4) = make_float4(sacc[jb][4], sacc[jb][5], sacc[jb][6], sacc[jb][7]);
        }
    }
}

// ---------------------------------------------------------------------------
// Fast pass (R12): streams precomputed fp16 u_hat. 1 b/thread; wave owns one
// (b, i-chunk): all loads/stores wave-contiguous 2 KB. ALL 9 u_hat rows are
// prefetched to registers first (static-indexed, full unroll), then 9
// mutually-independent softmax chains run back-to-back — ILP(9) x 32 waves/CU
// breaks the per-iteration dependent-chain latency that R0..R11 never varied.
// Grid (NIC, NBGF) = 2048 blocks x 256 thr.
// ---------------------------------------------------------------------------
template<int PASS>
__global__ __launch_bounds__(256)
void fast_pass_kernel(const _Float16* __restrict__ uhat,
                      const float* __restrict__ pv0, const float* __restrict__ pv1,
                      float* __restrict__ out)
{
    const int tid  = threadIdx.x;
    const int o    = tid & 31;
    const int hh   = (tid >> 5) & 1;
    const int bq   = tid >> 6;                 // 0..3 (wave id)
    const int b    = blockIdx.y * NBBF + bq;   // 1 b per thread
    const int i0   = blockIdx.x * IC;
    const int hofs = hh * 8;

    // Prefetch all 9 u_hat rows into registers (independent loads, hoisted).
    half8 hv[IC];
    #pragma unroll
    for (int ii = 0; ii < IC; ii++)
        hv[ii] = *(const half8*)
            (uhat + (((size_t)b * II + (i0 + ii)) * OO + o) * HH + hofs);

    // vsum (loads overlap the u_hat prefetch window).
    float vsum[8];
    {
        const float* p = pv0 + ((b * OO + o) * HH + hofs);
        float4 a = *(const float4*)p;
        float4 c = *(const float4*)(p + 4);
        vsum[0] = a.x; vsum[1] = a.y; vsum[2] = a.z; vsum[3] = a.w;
        vsum[4] = c.x; vsum[5] = c.y; vsum[6] = c.z; vsum[7] = c.w;
        if (PASS == 2) {
            const float* q = pv1 + ((b * OO + o) * HH + hofs);
            float4 a2 = *(const float4*)q;
            float4 c2 = *(const float4*)(q + 4);
            vsum[0] += a2.x; vsum[1] += a2.y; vsum[2] += a2.z; vsum[3] += a2.w;
            vsum[4] += c2.x; vsum[5] += c2.y; vsum[6] += c2.z; vsum[7] += c2.w;
        }
    }

    float sacc[8];
    #pragma unroll
    for (int h2 = 0; h2 < 8; h2++) sacc[h2] = 0.f;

    // 9 independent softmax chains (scheduler interleaves them).
    #pragma unroll
    for (int ii = 0; ii < IC; ii++) {
        float uh[8];
        #pragma unroll
        for (int h2 = 0; h2 < 8; h2++) uh[h2] = (float)hv[ii][h2];

        float lg = 0.f;
        #pragma unroll
        for (int h2 = 0; h2 < 8; h2++)
            lg = fmaf(vsum[h2], uh[h2], lg);
        lg = add_xor32(lg);                    // h-half combine (VALU)
        const float e = __expf(lg);
        const float se = add_xor16(row_sum16(e));  // sum over 32 o-lanes
        const float cc = __fdividef(e, se);

        #pragma unroll
        for (int h2 = 0; h2 < 8; h2++)
            sacc[h2] = fmaf(cc, uh[h2], sacc[h2]);
    }

    float* p = out + ((size_t)blockIdx.x * BB + b) * (OO * HH) + o * HH + hofs;
    *(float4*)p       = make_float4(sacc[0], sacc[1], sacc[2], sacc[3]);
    *(float4*)(p + 4) = make_float4(sacc[4], sacc[5], sacc[6], sacc[7]);
}

// ---------------------------------------------------------------------------
// Fused reduce-over-chunks + squash (R4-proven): 256 blocks spread the
// 16.8 MB partial read over the whole chip.
// ---------------------------------------------------------------------------
__global__ __launch_bounds__(256)
void reduce_squash_wide_kernel(const float* __restrict__ part, float* __restrict__ v)
{
    const int t4l = threadIdx.x & 31;
    const int icp = threadIdx.x >> 5;
    const int t4  = blockIdx.x * 32 + t4l;

    const float4* p = (const float4*)part + t4;
    float4 acc = make_float4(0.f, 0.f, 0.f, 0.f);
    #pragma unroll
    for (int k = 0; k < NIC / 8; k++) {
        float4 x = p[(size_t)(icp * (NIC / 8) + k) * (BOH / 4)];
        acc.x += x.x; acc.y += x.y; acc.z += x.z; acc.w += x.w;
    }

    __shared__ float4 red[8][32];
    red[icp][t4l] = acc;
    __syncthreads();

    if (threadIdx.x < 32) {
        float4 a = red[0][t4l];
        #pragma unroll
        for (int j = 1; j < 8; j++) {
            float4 x = red[j][t4l];
            a.x += x.x; a.y += x.y; a.z += x.z; a.w += x.w;
        }
        float sq = a.x * a.x + a.y * a.y + a.z * a.z + a.w * a.w;
        sq = dpp_add<0xB1>(sq);   // quad_perm [1,0,3,2]
        sq = dpp_add<0x4E>(sq);   // quad_perm [2,3,0,1]
        const float scale = (sq / (1.f + sq)) * rsqrtf(sq + 1e-8f);
        a.x *= scale; a.y *= scale; a.z *= scale; a.w *= scale;
        ((float4*)v)[t4] = a;
    }
}

// Standalone squash for the atomic tiny-ws fallback.
__global__ __launch_bounds__(256)
void squash_kernel(const float* __restrict__ s, float* __restrict__ v)
{
    const int t = blockIdx.x * blockDim.x + threadIdx.x;
    if (t >= BB * OO) return;
    const float4* sp = (const float4*)(s + t * HH);
    float4 a = sp[0], b = sp[1], c = sp[2], d = sp[3];
    float sq = a.x*a.x + a.y*a.y + a.z*a.z + a.w*a.w
             + b.x*b.x + b.y*b.y + b.z*b.z + b.w*b.w
             + c.x*c.x + c.y*c.y + c.z*c.z + c.w*c.w
             + d.x*d.x + d.y*d.y + d.z*d.z + d.w*d.w;
    const float scale = (sq / (1.f + sq)) * rsqrtf(sq + 1e-8f);
    a.x *= scale; a.y *= scale; a.z *= scale; a.w *= scale;
    b.x *= scale; b.y *= scale; b.z *= scale; b.w *= scale;
    c.x *= scale; c.y *= scale; c.z *= scale; c.w *= scale;
    d.x *= scale; d.y *= scale; d.z *= scale; d.w *= scale;
    float4* vp = (float4*)(v + t * HH);
    vp[0] = a; vp[1] = b; vp[2] = c; vp[3] = d;
}

extern "C" void kernel_launch(void* const* d_in, const int* in_sizes, int n_in,
                              void* d_out, int out_size, void* d_ws, size_t ws_size,
                              hipStream_t stream)
{
    (void)in_sizes; (void)n_in; (void)out_size;
    const float* u = (const float*)d_in[0];
    const float* w = (const float*)d_in[1];
    float* out = (float*)d_out;

    const size_t partN = (size_t)NIC * BOH;
    const size_t need  = (partN + 2 * BOH) * sizeof(float) + UHN * sizeof(_Float16);
    const dim3 blk(256);

    if (ws_size >= need) {
        // 6 dispatches: producer pass 0 (writes fp16 u_hat) + 2 streaming
        // passes + 3 wide reduces.
        float* part     = (float*)d_ws;
        float* v0       = part + partN;
        float* v1       = v0 + BOH;
        _Float16* uhat  = (_Float16*)(v1 + BOH);    // 16-B aligned offset
        const int rblocks = BOH / 4 / 32;           // 256 blocks

        pass_kernel<0, false, true><<<dim3(NIC, NBG), blk, 0, stream>>>(
            u, w, nullptr, nullptr, part, uhat);
        reduce_squash_wide_kernel<<<rblocks, 256, 0, stream>>>(part, v0);
        fast_pass_kernel<1><<<dim3(NIC, NBGF), blk, 0, stream>>>(uhat, v0, nullptr, part);
        reduce_squash_wide_kernel<<<rblocks, 256, 0, stream>>>(part, v1);
        fast_pass_kernel<2><<<dim3(NIC, NBGF), blk, 0, stream>>>(uhat, v0, v1, part);
        reduce_squash_wide_kernel<<<rblocks, 256, 0, stream>>>(part, out);
    } else {
        // Tiny-ws fallback: R5-exact atomic path.
        float* s0 = (float*)d_ws;
        float* s1 = s0 + BOH;
        float* v0 = s1 + BOH;
        float* v1 = v0 + BOH;
        hipMemsetAsync(d_ws, 0, 2 * BOH * sizeof(float), stream);
        hipMemsetAsync(d_out, 0, BOH * sizeof(float), stream);
        const dim3 grid(NIC, NBG);
        const int sq_blocks = (BB * OO + 255) / 256;

        pass_kernel<0, true, false><<<grid, blk, 0, stream>>>(u, w, nullptr, nullptr, s0, nullptr);
        squash_kernel<<<sq_blocks, 256, 0, stream>>>(s0, v0);
        pass_kernel<1, true, false><<<grid, blk, 0, stream>>>(u, w, v0, nullptr, s1, nullptr);
        squash_kernel<<<sq_blocks, 256, 0, stream>>>(s1, v1);
        pass_kernel<2, true, false><<<grid, blk, 0, stream>>>(u, w, v0, v1, out, nullptr);
        squash_kernel<<<sq_blocks, 256, 0, stream>>>(out, out);
    }
}

// Round 13
// 121.102 us; speedup vs baseline: 3.3302x; 1.0507x over previous
//
#include <hip/hip_runtime.h>

// Problem constants
#define BB 64
#define II 1152
#define OO 32
#define DD 8
#define HH 16
#define BOH (BB * OO * HH)    // 32768
#define WTILE (OO * DD * HH)  // 4096 floats per i

// Producer / fallback decomposition (R5-exact): NIC * IC == II, 512 blocks.
#define IC   9
#define NIC  128
#define NBB  16    // b per block
#define NBG  4     // b-groups
#define NJB  4     // b per thread

// Fast-pass decomposition (R13): grid (NRNG, BB) = 2048 blocks; block owns
// (i-range of 36, one b); wave q handles a 9-i subgroup (R12's proven ILP
// unit); the 4 waves' partials are LDS-tree-summed in-block -> part slab
// shrinks 128 -> 32 chunks (16.8 -> 4.2 MB), reduces 1/2 shrink to match.
#define NRNG 32
#define ICR  (II / NRNG)   // 36

typedef _Float16 half8 __attribute__((ext_vector_type(8)));

// u_hat element count (fp16): 75.5 MB
#define UHN ((size_t)BB * II * OO * HH)

// ---------------------------------------------------------------------------
// DPP add helper (ctrl must be an ICE -> template param).
// ---------------------------------------------------------------------------
template<int CTRL>
__device__ __forceinline__ float dpp_add(float x)
{
    return x + __int_as_float(__builtin_amdgcn_update_dpp(
            0, __float_as_int(x), CTRL, 0xF, 0xF, false));
}

// Sum over each 16-lane row, result in every lane of the row (VALU only).
__device__ __forceinline__ float row_sum16(float x)
{
    x = dpp_add<0x121>(x);   // row_ror:1
    x = dpp_add<0x122>(x);   // row_ror:2
    x = dpp_add<0x124>(x);   // row_ror:4
    x = dpp_add<0x128>(x);   // row_ror:8
    return x;
}

// lane l gets x[l] + x[l^32] — VALU permlane32_swap.
__device__ __forceinline__ float add_xor32(float x)
{
#if __has_builtin(__builtin_amdgcn_permlane32_swap)
    auto r = __builtin_amdgcn_permlane32_swap(
        __float_as_uint(x), __float_as_uint(x), false, false);
    return __uint_as_float(r[0]) + __uint_as_float(r[1]);
#else
    return x + __shfl_xor(x, 32, 64);
#endif
}

// lane l gets x[l] + x[l^16] — VALU permlane16_swap.
__device__ __forceinline__ float add_xor16(float x)
{
#if __has_builtin(__builtin_amdgcn_permlane16_swap)
    auto r = __builtin_amdgcn_permlane16_swap(
        __float_as_uint(x), __float_as_uint(x), false, false);
    return __uint_as_float(r[0]) + __uint_as_float(r[1]);
#else
    return x + __int_as_float(__builtin_amdgcn_ds_swizzle(__float_as_int(x), 0x401F));
#endif
}

// ---------------------------------------------------------------------------
// 5-bit XOR swizzle within one 4096-float W tile (involution; 16-B groups
// contiguous; read-side bank histogram uniform 8/bank -> conflict-free).
// ---------------------------------------------------------------------------
__device__ __forceinline__ int wswz(int f) { return f ^ (((f >> 7) & 31) << 2); }

// Stage one 16 KB W tile global->LDS via DMA (linear dest, pre-swizzled src).
__device__ __forceinline__ void stage_w_tile(const float* __restrict__ wg,
                                             float* __restrict__ wn, int tid)
{
    #pragma unroll
    for (int j = 0; j < 4; j++) {
        const int P = (tid + j * 256) * 4;
        const int g = wswz(P);
        __builtin_amdgcn_global_load_lds(
            (const __attribute__((address_space(1))) void*)(wg + g),
            (__attribute__((address_space(3))) void*)(wn + P),
            16, 0, 0);
    }
}

// ---------------------------------------------------------------------------
// Producer pass (R5-proven body). UHAT=true additionally stores u_hat as fp16
// (wave-contiguous rows per (b,i)) for the fast passes to stream.
// Grid (NIC, NBG) = 512 blocks x 256 thr; tid = o + 32*hh + 64*bq.
// ---------------------------------------------------------------------------
template<int PASS, bool ATOMIC, bool UHAT>
__global__ __launch_bounds__(256)
void pass_kernel(const float* __restrict__ u, const float* __restrict__ w,
                 const float* __restrict__ pv0, const float* __restrict__ pv1,
                 float* __restrict__ out, _Float16* __restrict__ uhat)
{
    __shared__ __align__(16) float Wsh[2][WTILE];   // 2 x 16 KB, linear

    const int tid   = threadIdx.x;
    const int o     = tid & 31;
    const int hh    = (tid >> 5) & 1;
    const int bq    = tid >> 6;           // 0..3
    const int bbase = blockIdx.y * NBB;
    const int i0    = blockIdx.x * IC;
    const int hofs  = hh * 8;
    const int swm   = o << 2;             // read-side XOR (floats), 5-bit
    const int orow  = o * (DD * HH);

    stage_w_tile(w + (size_t)i0 * WTILE, Wsh[0], tid);

    float vsum[NJB][8];
    if (PASS >= 1) {
        #pragma unroll
        for (int jb = 0; jb < NJB; jb++) {
            const int b = bbase + bq * NJB + jb;
            const float* p = pv0 + ((b * OO + o) * HH + hofs);
            float4 a = *(const float4*)p;
            float4 c = *(const float4*)(p + 4);
            vsum[jb][0] = a.x; vsum[jb][1] = a.y; vsum[jb][2] = a.z; vsum[jb][3] = a.w;
            vsum[jb][4] = c.x; vsum[jb][5] = c.y; vsum[jb][6] = c.z; vsum[jb][7] = c.w;
            if (PASS == 2) {
                const float* q = pv1 + ((b * OO + o) * HH + hofs);
                float4 a2 = *(const float4*)q;
                float4 c2 = *(const float4*)(q + 4);
                vsum[jb][0] += a2.x; vsum[jb][1] += a2.y; vsum[jb][2] += a2.z; vsum[jb][3] += a2.w;
                vsum[jb][4] += c2.x; vsum[jb][5] += c2.y; vsum[jb][6] += c2.z; vsum[jb][7] += c2.w;
            }
        }
    }

    float sacc[NJB][8];
    #pragma unroll
    for (int jb = 0; jb < NJB; jb++)
        #pragma unroll
        for (int h2 = 0; h2 < 8; h2++) sacc[jb][h2] = 0.f;

    __syncthreads();   // drains vmcnt(0): Wsh[0] DMA complete

    for (int ii = 0; ii < IC; ii++) {
        const float* wcur = Wsh[ii & 1];

        if (ii + 1 < IC)
            stage_w_tile(w + (size_t)(i0 + ii + 1) * WTILE, Wsh[(ii + 1) & 1], tid);

        float us[NJB][8];
        #pragma unroll
        for (int jb = 0; jb < NJB; jb++) {
            const float* ub = u + ((size_t)(bbase + bq * NJB + jb) * II + (i0 + ii)) * DD;
            float4 a = *(const float4*)ub;
            float4 c = *(const float4*)(ub + 4);
            us[jb][0] = a.x; us[jb][1] = a.y; us[jb][2] = a.z; us[jb][3] = a.w;
            us[jb][4] = c.x; us[jb][5] = c.y; us[jb][6] = c.z; us[jb][7] = c.w;
        }

        float uh[NJB][8];
        #pragma unroll
        for (int jb = 0; jb < NJB; jb++)
            #pragma unroll
            for (int h2 = 0; h2 < 8; h2++) uh[jb][h2] = 0.f;
        #pragma unroll
        for (int d = 0; d < DD; d++) {
            const int ba  = (d * HH + hofs    ) ^ swm;
            const int bb2 = (d * HH + hofs + 4) ^ swm;
            float4 wa = *(const float4*)&wcur[orow + ba];
            float4 wb = *(const float4*)&wcur[orow + bb2];
            const float wv[8] = {wa.x, wa.y, wa.z, wa.w, wb.x, wb.y, wb.z, wb.w};
            #pragma unroll
            for (int jb = 0; jb < NJB; jb++)
                #pragma unroll
                for (int h2 = 0; h2 < 8; h2++)
                    uh[jb][h2] = fmaf(us[jb][d], wv[h2], uh[jb][h2]);
        }

        // Store u_hat (fp16): wave-contiguous rows, overlaps next DMA.
        if (UHAT) {
            #pragma unroll
            for (int jb = 0; jb < NJB; jb++) {
                const int b = bbase + bq * NJB + jb;
                half8 hv;
                #pragma unroll
                for (int h2 = 0; h2 < 8; h2++) hv[h2] = (_Float16)uh[jb][h2];
                *(half8*)(uhat + (((size_t)b * II + (i0 + ii)) * OO + o) * HH + hofs) = hv;
            }
        }

        float cc[NJB];
        if (PASS == 0) {
            #pragma unroll
            for (int jb = 0; jb < NJB; jb++) cc[jb] = 1.0f / 32.0f;
        } else {
            #pragma unroll
            for (int jb = 0; jb < NJB; jb++) {
                float lg = 0.f;
                #pragma unroll
                for (int h2 = 0; h2 < 8; h2++)
                    lg = fmaf(vsum[jb][h2], uh[jb][h2], lg);
                lg = add_xor32(lg);
                const float e = __expf(lg);
                const float se = add_xor16(row_sum16(e));
                cc[jb] = __fdividef(e, se);
            }
        }

        #pragma unroll
        for (int jb = 0; jb < NJB; jb++)
            #pragma unroll
            for (int h2 = 0; h2 < 8; h2++)
                sacc[jb][h2] = fmaf(cc[jb], uh[jb][h2], sacc[jb][h2]);

        __syncthreads();
    }

    #pragma unroll
    for (int jb = 0; jb < NJB; jb++) {
        const int b = bbase + bq * NJB + jb;
        if (ATOMIC) {
            float* p = out + ((b * OO + o) * HH + hofs);
            #pragma unroll
            for (int h2 = 0; h2 < 8; h2++) atomicAdd(p + h2, sacc[jb][h2]);
        } else {
            float* p = out + ((size_t)blockIdx.x * BB + b) * (OO * HH) + o * HH + hofs;
            *(float4*)p       = make_float4(sacc[jb][0], sacc[jb][1], sacc[jb][2], sacc[jb][3]);
            *(float4*)(p + 4) = make_float4(sacc[jb][4], sacc[jb][5], sacc[jb][6], sacc[jb][7]);
        }
    }
}

// ---------------------------------------------------------------------------
// Fast pass (R13): streams precomputed fp16 u_hat. Block = (i-range of 36,
// one b); wave q owns a 9-i subgroup (R12's ILP unit: 9 rows prefetched to
// registers, 9 independent softmax chains). The 4 waves' partials are summed
// in-block via an 8 KB LDS tree -> part is 32 chunks (4.2 MB) not 128.
// Grid (NRNG, BB) = 2048 blocks x 256 thr (8 blocks/CU).
// ---------------------------------------------------------------------------
template<int PASS>
__global__ __launch_bounds__(256)
void fast_pass_kernel(const _Float16* __restrict__ uhat,
                      const float* __restrict__ pv0, const float* __restrict__ pv1,
                      float* __restrict__ part)
{
    __shared__ float4 red[4][64][2];   // 8 KB

    const int tid  = threadIdx.x;
    const int o    = tid & 31;
    const int hh   = (tid >> 5) & 1;
    const int q    = tid >> 6;               // wave = 9-i subgroup
    const int b    = blockIdx.y;
    const int i0   = blockIdx.x * ICR + q * 9;
    const int hofs = hh * 8;

    // Prefetch all 9 u_hat rows into registers (independent loads, hoisted).
    half8 hv[9];
    #pragma unroll
    for (int ii = 0; ii < 9; ii++)
        hv[ii] = *(const half8*)
            (uhat + (((size_t)b * II + (i0 + ii)) * OO + o) * HH + hofs);

    // vsum (loads overlap the u_hat prefetch window).
    float vsum[8];
    {
        const float* p = pv0 + ((b * OO + o) * HH + hofs);
        float4 a = *(const float4*)p;
        float4 c = *(const float4*)(p + 4);
        vsum[0] = a.x; vsum[1] = a.y; vsum[2] = a.z; vsum[3] = a.w;
        vsum[4] = c.x; vsum[5] = c.y; vsum[6] = c.z; vsum[7] = c.w;
        if (PASS == 2) {
            const float* qq = pv1 + ((b * OO + o) * HH + hofs);
            float4 a2 = *(const float4*)qq;
            float4 c2 = *(const float4*)(qq + 4);
            vsum[0] += a2.x; vsum[1] += a2.y; vsum[2] += a2.z; vsum[3] += a2.w;
            vsum[4] += c2.x; vsum[5] += c2.y; vsum[6] += c2.z; vsum[7] += c2.w;
        }
    }

    float sacc[8];
    #pragma unroll
    for (int h2 = 0; h2 < 8; h2++) sacc[h2] = 0.f;

    // 9 independent softmax chains (scheduler interleaves them).
    #pragma unroll
    for (int ii = 0; ii < 9; ii++) {
        float uh[8];
        #pragma unroll
        for (int h2 = 0; h2 < 8; h2++) uh[h2] = (float)hv[ii][h2];

        float lg = 0.f;
        #pragma unroll
        for (int h2 = 0; h2 < 8; h2++)
            lg = fmaf(vsum[h2], uh[h2], lg);
        lg = add_xor32(lg);                    // h-half combine (VALU)
        const float e = __expf(lg);
        const float se = add_xor16(row_sum16(e));  // sum over 32 o-lanes
        const float cc = __fdividef(e, se);

        #pragma unroll
        for (int h2 = 0; h2 < 8; h2++)
            sacc[h2] = fmaf(cc, uh[h2], sacc[h2]);
    }

    // In-block sum over the 4 waves' 9-i subgroups (LDS tree).
    red[q][o + 32 * hh][0] = make_float4(sacc[0], sacc[1], sacc[2], sacc[3]);
    red[q][o + 32 * hh][1] = make_float4(sacc[4], sacc[5], sacc[6], sacc[7]);
    __syncthreads();

    if (tid < 64) {   // one thread per (o,hh); o = tid&31, hh = tid>>5
        float4 a = red[0][tid][0], c = red[0][tid][1];
        #pragma unroll
        for (int j = 1; j < 4; j++) {
            float4 x = red[j][tid][0], y = red[j][tid][1];
            a.x += x.x; a.y += x.y; a.z += x.z; a.w += x.w;
            c.x += y.x; c.y += y.y; c.z += y.z; c.w += y.w;
        }
        float* p = part + ((size_t)blockIdx.x * BB + b) * (OO * HH)
                 + (tid & 31) * HH + (tid >> 5) * 8;
        *(float4*)p       = a;
        *(float4*)(p + 4) = c;
    }
}

// ---------------------------------------------------------------------------
// Fused reduce-over-chunks + squash, templated on chunk count.
// 256 blocks; block handles 32 consecutive float4 elements of [b][o][h];
// NCH chunks split 8-ways (icp), LDS tree combines, quad-DPP squash.
// ---------------------------------------------------------------------------
template<int NCH>
__global__ __launch_bounds__(256)
void reduce_squash_wide_kernel(const float* __restrict__ part, float* __restrict__ v)
{
    const int t4l = threadIdx.x & 31;
    const int icp = threadIdx.x >> 5;
    const int t4  = blockIdx.x * 32 + t4l;

    const float4* p = (const float4*)part + t4;
    float4 acc = make_float4(0.f, 0.f, 0.f, 0.f);
    #pragma unroll
    for (int k = 0; k < NCH / 8; k++) {
        float4 x = p[(size_t)(icp * (NCH / 8) + k) * (BOH / 4)];
        acc.x += x.x; acc.y += x.y; acc.z += x.z; acc.w += x.w;
    }

    __shared__ float4 red[8][32];
    red[icp][t4l] = acc;
    __syncthreads();

    if (threadIdx.x < 32) {
        float4 a = red[0][t4l];
        #pragma unroll
        for (int j = 1; j < 8; j++) {
            float4 x = red[j][t4l];
            a.x += x.x; a.y += x.y; a.z += x.z; a.w += x.w;
        }
        float sq = a.x * a.x + a.y * a.y + a.z * a.z + a.w * a.w;
        sq = dpp_add<0xB1>(sq);   // quad_perm [1,0,3,2]
        sq = dpp_add<0x4E>(sq);   // quad_perm [2,3,0,1]
        const float scale = (sq / (1.f + sq)) * rsqrtf(sq + 1e-8f);
        a.x *= scale; a.y *= scale; a.z *= scale; a.w *= scale;
        ((float4*)v)[t4] = a;
    }
}

// Standalone squash for the atomic tiny-ws fallback.
__global__ __launch_bounds__(256)
void squash_kernel(const float* __restrict__ s, float* __restrict__ v)
{
    const int t = blockIdx.x * blockDim.x + threadIdx.x;
    if (t >= BB * OO) return;
    const float4* sp = (const float4*)(s + t * HH);
    float4 a = sp[0], b = sp[1], c = sp[2], d = sp[3];
    float sq = a.x*a.x + a.y*a.y + a.z*a.z + a.w*a.w
             + b.x*b.x + b.y*b.y + b.z*b.z + b.w*b.w
             + c.x*c.x + c.y*c.y + c.z*c.z + c.w*c.w
             + d.x*d.x + d.y*d.y + d.z*d.z + d.w*d.w;
    const float scale = (sq / (1.f + sq)) * rsqrtf(sq + 1e-8f);
    a.x *= scale; a.y *= scale; a.z *= scale; a.w *= scale;
    b.x *= scale; b.y *= scale; b.z *= scale; b.w *= scale;
    c.x *= scale; c.y *= scale; c.z *= scale; c.w *= scale;
    d.x *= scale; d.y *= scale; d.z *= scale; d.w *= scale;
    float4* vp = (float4*)(v + t * HH);
    vp[0] = a; vp[1] = b; vp[2] = c; vp[3] = d;
}

extern "C" void kernel_launch(void* const* d_in, const int* in_sizes, int n_in,
                              void* d_out, int out_size, void* d_ws, size_t ws_size,
                              hipStream_t stream)
{
    (void)in_sizes; (void)n_in; (void)out_size;
    const float* u = (const float*)d_in[0];
    const float* w = (const float*)d_in[1];
    float* out = (float*)d_out;

    const size_t partN = (size_t)NIC * BOH;   // sized for the 128-chunk producer slab
    const size_t need  = (partN + 2 * BOH) * sizeof(float) + UHN * sizeof(_Float16);
    const dim3 blk(256);

    if (ws_size >= need) {
        // 6 dispatches: producer pass 0 (writes fp16 u_hat) + 2 streaming
        // passes (in-block i-reduction -> 32-chunk slab) + 3 reduces.
        float* part     = (float*)d_ws;
        float* v0       = part + partN;
        float* v1       = v0 + BOH;
        _Float16* uhat  = (_Float16*)(v1 + BOH);    // 16-B aligned offset
        const int rblocks = BOH / 4 / 32;           // 256 blocks

        pass_kernel<0, false, true><<<dim3(NIC, NBG), blk, 0, stream>>>(
            u, w, nullptr, nullptr, part, uhat);
        reduce_squash_wide_kernel<NIC><<<rblocks, 256, 0, stream>>>(part, v0);
        fast_pass_kernel<1><<<dim3(NRNG, BB), blk, 0, stream>>>(uhat, v0, nullptr, part);
        reduce_squash_wide_kernel<NRNG><<<rblocks, 256, 0, stream>>>(part, v1);
        fast_pass_kernel<2><<<dim3(NRNG, BB), blk, 0, stream>>>(uhat, v0, v1, part);
        reduce_squash_wide_kernel<NRNG><<<rblocks, 256, 0, stream>>>(part, out);
    } else {
        // Tiny-ws fallback: R5-exact atomic path.
        float* s0 = (float*)d_ws;
        float* s1 = s0 + BOH;
        float* v0 = s1 + BOH;
        float* v1 = v0 + BOH;
        hipMemsetAsync(d_ws, 0, 2 * BOH * sizeof(float), stream);
        hipMemsetAsync(d_out, 0, BOH * sizeof(float), stream);
        const dim3 grid(NIC, NBG);
        const int sq_blocks = (BB * OO + 255) / 256;

        pass_kernel<0, true, false><<<grid, blk, 0, stream>>>(u, w, nullptr, nullptr, s0, nullptr);
        squash_kernel<<<sq_blocks, 256, 0, stream>>>(s0, v0);
        pass_kernel<1, true, false><<<grid, blk, 0, stream>>>(u, w, v0, nullptr, s1, nullptr);
        squash_kernel<<<sq_blocks, 256, 0, stream>>>(s1, v1);
        pass_kernel<2, true, false><<<grid, blk, 0, stream>>>(u, w, v0, v1, out, nullptr);
        squash_kernel<<<sq_blocks, 256, 0, stream>>>(out, out);
    }
}